// Round 22
// baseline (464.761 us; speedup 1.0000x reference)
//
#include <hip/hip_runtime.h>
#include <cmath>

#define NT    8192      // B*N tokens
#define DIM_  1024
#define EXP_  7168
#define CD_   5120      // concat dim (4096 mlp + 1024 attn)
#define OD_   2048
#define MPAD  8704      // 68 row-tiles of 128 (8192 + worst-case group padding)
#define NRT   68        // row tiles (128) in sorted/padded space

typedef __attribute__((ext_vector_type(8))) short short8;
typedef __attribute__((ext_vector_type(4))) float f32x4;
typedef __attribute__((ext_vector_type(4))) unsigned short ushort4_t;

__device__ __forceinline__ unsigned short f2bf(float f) {
  union { float f; unsigned u; } v; v.f = f;
  return (unsigned short)((v.u + 0x7FFFu + ((v.u >> 16) & 1u)) >> 16);
}
__device__ __forceinline__ float bf2f(unsigned short u) {
  union { unsigned u; float f; } v; v.u = ((unsigned)u) << 16;
  return v.f;
}
// tanh-form GELU (|err| vs exact erf-GELU < 1e-3); exp + hw rcp, ~9 VALU ops
__device__ __forceinline__ float fast_gelu(float x) {
  float y = 1.5957691216f * (x + 0.044715f * x * x * x);   // 2 * 0.79788456 * (...)
  float e = __expf(y);
  float t = 1.f - 2.f * __builtin_amdgcn_rcpf(1.f + e);    // tanh(y/2)
  return 0.5f * x * (1.f + t);
}

#define MFMA16(a, b, c) __builtin_amdgcn_mfma_f32_16x16x32_bf16(a, b, c, 0, 0, 0)

// ======== expert sort (128-granular): count -> scan -> fill -> scatter ========
__global__ __launch_bounds__(256) void count_experts(const int* __restrict__ em,
                                                     int* __restrict__ blockCnt) {
  __shared__ int h[4];
  int tid = threadIdx.x;
  if (tid < 4) h[tid] = 0;
  __syncthreads();
  atomicAdd(&h[em[blockIdx.x * 256 + tid]], 1);
  __syncthreads();
  if (tid < 4) blockCnt[blockIdx.x * 4 + tid] = h[tid];
}

__global__ void scan_make(const int* __restrict__ blockCnt, int* __restrict__ desc) {
  if (threadIdx.x != 0) return;
  int cnt[4] = {0, 0, 0, 0};
  for (int b = 0; b < 32; b++)
    for (int e = 0; e < 4; e++) cnt[e] += blockCnt[b * 4 + e];
  int base[4]; int acc = 0;
  for (int e = 0; e < 4; e++) { base[e] = acc; acc += ((cnt[e] + 127) >> 7) << 7; }
  for (int e = 0; e < 4; e++) { desc[e] = base[e]; desc[4 + e] = cnt[e]; }
  for (int r = 0; r < NRT; r++) {
    int te = -1;
    for (int e = 0; e < 4; e++) {
      int lo = base[e] >> 7;
      int hi = (base[e] + (((cnt[e] + 127) >> 7) << 7)) >> 7;
      if (r >= lo && r < hi) te = e;
    }
    desc[8 + r] = te;
  }
  int run[4];
  for (int e = 0; e < 4; e++) run[e] = base[e];
  for (int b = 0; b < 32; b++)
    for (int e = 0; e < 4; e++) { desc[76 + b * 4 + e] = run[e]; run[e] += blockCnt[b * 4 + e]; }
}

__global__ __launch_bounds__(256) void fill_perm(int* __restrict__ perm) {
  int i = blockIdx.x * 256 + threadIdx.x;
  if (i < MPAD) perm[i] = -1;
}

__global__ __launch_bounds__(256) void scatter_perm(const int* __restrict__ em,
    const int* __restrict__ desc, int* __restrict__ perm, int* __restrict__ pos) {
  __shared__ int wsum[4][4];
  int tid = threadIdx.x;
  int wv = tid >> 6, ln = tid & 63;
  int t = blockIdx.x * 256 + tid;
  int e = em[t];
  int wrank = 0;
#pragma unroll
  for (int k = 0; k < 4; k++) {
    unsigned long long m = __ballot(e == k);
    if (ln == 0) wsum[wv][k] = __popcll(m);
    if (e == k) wrank = __popcll(m & ((1ull << ln) - 1ull));
  }
  __syncthreads();
  int off = desc[76 + blockIdx.x * 4 + e];
  for (int w = 0; w < wv; w++) off += wsum[w][e];
  int p = off + wrank;
  perm[p] = t;
  pos[t] = p;
}

// ---------------- fp32 -> bf16 convert ----------------
__global__ __launch_bounds__(256) void cvt_bf16(const float* __restrict__ in,
                                                unsigned short* __restrict__ out, int n) {
  int i = (blockIdx.x * 256 + threadIdx.x) * 4;
  if (i >= n) return;
  float4 v = *(const float4*)(in + i);
  ushort4_t o;
  o[0] = f2bf(v.x); o[1] = f2bf(v.y); o[2] = f2bf(v.z); o[3] = f2bf(v.w);
  *(ushort4_t*)(out + i) = o;
}

// ---------------- LN1 + expert input mask -> xn bf16 (SORTED rows) ---------------
__global__ __launch_bounds__(256) void ln1_kernel(const float* __restrict__ x,
    const float* __restrict__ w, const float* __restrict__ b,
    const int* __restrict__ emask, const int* __restrict__ pos,
    unsigned short* __restrict__ xn) {
  int wave = threadIdx.x >> 6, lane = threadIdx.x & 63;
  int t = blockIdx.x * 4 + wave;
  const float* xt = x + (size_t)t * DIM_;
  float4 v[4];
  float s = 0.f, s2 = 0.f;
#pragma unroll
  for (int i = 0; i < 4; i++) {
    v[i] = *(const float4*)(xt + i * 256 + lane * 4);
    s  += v[i].x + v[i].y + v[i].z + v[i].w;
    s2 += v[i].x * v[i].x + v[i].y * v[i].y + v[i].z * v[i].z + v[i].w * v[i].w;
  }
#pragma unroll
  for (int o = 1; o < 64; o <<= 1) { s += __shfl_xor(s, o); s2 += __shfl_xor(s2, o); }
  float mu = s * (1.f / 1024.f);
  float rs = rsqrtf(s2 * (1.f / 1024.f) - mu * mu + 1e-5f);
  int din = 1024 >> (3 - emask[t]);
  unsigned short* ot = xn + (size_t)pos[t] * DIM_;
#pragma unroll
  for (int i = 0; i < 4; i++) {
    int c0 = i * 256 + lane * 4;
    float fv[4] = { v[i].x, v[i].y, v[i].z, v[i].w };
    ushort4_t o;
#pragma unroll
    for (int j = 0; j < 4; j++) {
      int c = c0 + j;
      float val = (c < din) ? (fv[j] - mu) * rs * w[c] + b[c] : 0.f;
      o[j] = f2bf(val);
    }
    *(ushort4_t*)(ot + c0) = o;
  }
}

// ---- GEMM1: grouped 128x128 bf16, 2-slot double buffer, 3 blocks/CU (R7) -------
// K = 128<<e per row-tile; epilogue scatters q/kv/cc to ORIGINAL token rows.
// q is pre-scaled by 0.125*log2(e) so attention softmax runs in exp2 domain.
__global__ __launch_bounds__(256, 3) void gemm_grp1(
    const unsigned short* __restrict__ A, const unsigned short* __restrict__ W,
    const float* __restrict__ bias, const int* __restrict__ tdesc,
    const int* __restrict__ perm, unsigned short* __restrict__ out0,
    unsigned short* __restrict__ out1, unsigned short* __restrict__ out2) {
  __shared__ unsigned short lds[16384];          // 32 KiB: As[2][4096] | Bs[2][4096]
  unsigned short* As = lds;
  unsigned short* Bs = lds + 8192;
  const int r = blockIdx.y;
  const int e = tdesc[8 + r];
  if (e < 0) return;                             // pad tile (uniform exit)
  const int ntiles = 4 << e;                     // K = 128<<e, BK=32
  constexpr int KK = 1024;

  const int tid = threadIdx.x;
  const int lane = tid & 63;
  const int wave = tid >> 6;       // 0..3
  const int wm = wave >> 1, wn = wave & 1;
  const int lg = lane >> 4, lr = lane & 15;

  // XCD swizzle on col dim (56 % 8 == 0)
  constexpr int CPX = 56 >> 3;
  const int bx = (int)blockIdx.x;
  const int bn = (bx & 7) * CPX + (bx >> 3);
  const int n0 = bn * 128;
  const int m0 = r * 128;

  // staging source map (inverse of superrow XOR swizzle)
  const int s0g = tid >> 3,        s1g = (256 + tid) >> 3;
  const int lc0 = (tid & 7) ^ (s0g & 7), lc1 = (tid & 7) ^ (s1g & 7);
  const int row0 = 2 * s0g + (lc0 >> 2), kc0 = lc0 & 3;
  const int row1 = 2 * s1g + (lc1 >> 2), kc1 = lc1 & 3;
  const unsigned short* aS0 = A + (size_t)(m0 + row0) * KK + kc0 * 8;
  const unsigned short* aS1 = A + (size_t)(m0 + row1) * KK + kc1 * 8;
  const unsigned short* bS0 = W + (size_t)(n0 + row0) * KK + kc0 * 8;
  const unsigned short* bS1 = W + (size_t)(n0 + row1) * KK + kc1 * 8;

#define GLD(SRC, DST)                                                                \
  __builtin_amdgcn_global_load_lds(                                                  \
      (const __attribute__((address_space(1))) void*)(SRC),                          \
      (__attribute__((address_space(3))) void*)(DST), 16, 0, 0)
#define STAGE(T, SLOT) {                                                             \
    GLD(aS0 + (size_t)(T) * 32, As + (SLOT) * 4096 + tid * 8);                       \
    GLD(aS1 + (size_t)(T) * 32, As + (SLOT) * 4096 + 2048 + tid * 8);                \
    GLD(bS0 + (size_t)(T) * 32, Bs + (SLOT) * 4096 + tid * 8);                       \
    GLD(bS1 + (size_t)(T) * 32, Bs + (SLOT) * 4096 + 2048 + tid * 8);                \
  }

  const int fb = (lr >> 1) * 128 + ((((lr & 1) << 2) + lg) ^ ((lr >> 1) & 7)) * 16;
  const char* apb = (const char*)As + wm * 4096 + fb;
  const char* bpb = (const char*)Bs + wn * 4096 + fb;

  short8 afr[4], bfr[4];
#define LDFRAG(C)                                                                    \
  _Pragma("unroll") for (int mi = 0; mi < 4; mi++)                                   \
    afr[mi] = *(const short8*)(apb + (C) * 8192 + mi * 1024);                        \
  _Pragma("unroll") for (int ni = 0; ni < 4; ni++)                                   \
    bfr[ni] = *(const short8*)(bpb + (C) * 8192 + ni * 1024);

  f32x4 acc[4][4];
  f32x4 zf = { 0.f, 0.f, 0.f, 0.f };
#pragma unroll
  for (int i = 0; i < 4; i++)
#pragma unroll
    for (int j = 0; j < 4; j++) acc[i][j] = zf;

  STAGE(0, 0)
  STAGE(1, 1)
  asm volatile("s_waitcnt vmcnt(4)" ::: "memory");
  __builtin_amdgcn_s_barrier();

#pragma unroll 1
  for (int t = 0; t < ntiles; ++t) {
    const int c = t & 1;
    LDFRAG(c)
    asm volatile("s_waitcnt lgkmcnt(0)" ::: "memory");
    __builtin_amdgcn_sched_barrier(0);
    __builtin_amdgcn_s_barrier();
    const int t2 = (t + 2 < ntiles) ? t + 2 : t;
    STAGE(t2, c)
    __builtin_amdgcn_s_setprio(1);
#pragma unroll
    for (int mi = 0; mi < 4; mi++)
#pragma unroll
      for (int ni = 0; ni < 4; ni++)
        acc[mi][ni] = MFMA16(afr[mi], bfr[ni], acc[mi][ni]);
    __builtin_amdgcn_s_setprio(0);
    asm volatile("s_waitcnt vmcnt(4)" ::: "memory");
    __builtin_amdgcn_s_barrier();
  }
  asm volatile("s_waitcnt vmcnt(0)" ::: "memory");

  // epilogue: grow (sorted) = m0+wm*64+mi*16+lg*4+rr ; gcol = n0w+ni*16+lr
  // region is uniform per wave (64-col slice, boundaries 64-aligned)
  const int n0w = n0 + wn * 64;
  auto epi_loop = [&](auto&& body) {
#pragma unroll
    for (int mi = 0; mi < 4; mi++)
#pragma unroll
      for (int ni = 0; ni < 4; ni++)
#pragma unroll
        for (int rr = 0; rr < 4; rr++) {
          int grow = m0 + wm * 64 + mi * 16 + lg * 4 + rr;
          int tk = perm[grow];
          int gcol = n0w + ni * 16 + lr;
          body(tk, gcol, acc[mi][ni][rr]);
        }
  };
  if (n0w < 1024) {                    // q: scaled (0.125*log2e), head-major
    epi_loop([&](int tk, int gcol, float v) {
      if (tk >= 0) {
        float vv = (v + bias[gcol]) * 0.18033688f;   // 0.125 * log2(e)
        int bb = tk >> 10;
        int n = tk & 1023;
        int h = gcol >> 6;
        int d = gcol & 63;
        out0[(((size_t)(bb * 16 + h) * 1024 + n) << 6) + d] = f2bf(vv);
      }
    });
  } else if (n0w < 3072) {             // kv (pre-LN2)
    epi_loop([&](int tk, int gcol, float v) {
      if (tk >= 0) out1[(size_t)tk * OD_ + (gcol - 1024)] = f2bf(v + bias[gcol]);
    });
  } else {                             // mlp hidden -> fast gelu -> cc
    const bool hasb = (n0w < 4096);    // bias covers cols [0,4096) only
    epi_loop([&](int tk, int gcol, float v) {
      if (tk >= 0) {
        float vb = v + (hasb ? bias[gcol] : 0.f);
        out2[(size_t)tk * CD_ + (gcol - 3072)] = f2bf(fast_gelu(vb));
      }
    });
  }
#undef GLD
#undef STAGE
#undef LDFRAG
}

// ---- GEMM2: expert-sparse split-K 256x256 8-phase over SORTED rows -------------
// Row tile r = sorted rows [256r,256r+256); A-rows gathered via perm.
// Col-tiles bn >= 2^emax exit; bn rotated by r for XCD balance; split-K=2.
__global__ __launch_bounds__(512, 2) void gemm2_8p(
    const unsigned short* __restrict__ A, const unsigned short* __restrict__ W,
    const int* __restrict__ tdesc, const int* __restrict__ perm,
    unsigned short* __restrict__ pk0, unsigned short* __restrict__ pk1) {
  extern __shared__ unsigned short lds[];
  unsigned short* As = lds;            // [2 slots][16384] elems
  unsigned short* Bs = lds + 32768;
  constexpr int KK = 5120;
  constexpr int NTILES = 40;           // K half = 2560, BK=64
  const int r = blockIdx.y;            // 256-row sorted tile (34 total)
  const int ea = tdesc[8 + 2 * r];
  const int eb = tdesc[8 + 2 * r + 1];
  const int emax = (ea > eb) ? ea : eb;
  if (emax < 0) return;                // both halves pad (uniform exit)
  const int bn = ((int)blockIdx.x + r) & 7;     // rotated col-tile for XCD spread
  if (bn >= (1 << emax)) return;                // masked-out output cols
  const int k0 = (int)blockIdx.z * 2560;

  const int tid = threadIdx.x;
  const int lane = tid & 63;
  const int wave = tid >> 6;   // 0..7
  const int wm = wave >> 2;    // 0..1
  const int wn = wave & 3;     // 0..3
  const int lg = lane >> 4, lr = lane & 15;
  const int m0 = r * 256, n0 = bn * 256;

  const int srow = tid >> 3;
  const int schunk = (tid & 7) ^ (srow & 7);
  // A-row gather via perm (pad rows clamp to row 0; their outputs never gathered)
  const unsigned short* aSrcS[4];
#pragma unroll
  for (int s4 = 0; s4 < 4; s4++) {
    int tk = perm[m0 + s4 * 64 + srow];
    if (tk < 0) tk = 0;
    aSrcS[s4] = A + (size_t)tk * KK + k0 + schunk * 8;
  }
  const unsigned short* bSrc = W + (size_t)(n0 + srow) * KK + k0 + schunk * 8;

  const int xor0 = (lg ^ (lr & 7)) * 8;
  const int xor1 = ((4 + lg) ^ (lr & 7)) * 8;
  const unsigned short* ap0 = As + (wm * 64 + lr) * 64 + xor0;
  const unsigned short* ap1 = As + (wm * 64 + lr) * 64 + xor1;
  const unsigned short* bp0 = Bs + (wn * 32 + lr) * 64 + xor0;
  const unsigned short* bp1 = Bs + (wn * 32 + lr) * 64 + xor1;

#define STAGE_A(TT, SLOT, SEG)                                                       \
  __builtin_amdgcn_global_load_lds(                                                  \
    (const __attribute__((address_space(1))) void*)(aSrcS[SEG] +                     \
      (size_t)(TT) * 64),                                                            \
    (__attribute__((address_space(3))) void*)(As + (SLOT) * 16384 +                  \
      (SEG) * 4096 + tid * 8), 16, 0, 0)
#define STAGE_B(TT, SLOT, SEG)                                                       \
  __builtin_amdgcn_global_load_lds(                                                  \
    (const __attribute__((address_space(1))) void*)(bSrc +                           \
      (size_t)(SEG) * 64 * KK + (size_t)(TT) * 64),                                  \
    (__attribute__((address_space(3))) void*)(Bs + (SLOT) * 16384 +                  \
      (SEG) * 4096 + tid * 8), 16, 0, 0)

  short8 afr[4][2], bfr[2][2][2];
#define LDFRAG_A(C, QM)                                                              \
  _Pragma("unroll") for (int mi = 0; mi < 4; mi++) {                                 \
    afr[mi][0] = *(const short8*)(ap0 + (C) * 16384 + (QM) * 8192 + mi * 1024);      \
    afr[mi][1] = *(const short8*)(ap1 + (C) * 16384 + (QM) * 8192 + mi * 1024);      \
  }
#define LDFRAG_B(C, QN)                                                              \
  _Pragma("unroll") for (int ni = 0; ni < 2; ni++) {                                 \
    bfr[QN][ni][0] = *(const short8*)(bp0 + (C) * 16384 + (QN) * 8192 + ni * 1024);  \
    bfr[QN][ni][1] = *(const short8*)(bp1 + (C) * 16384 + (QN) * 8192 + ni * 1024);  \
  }
#define DOMFMA(QM, QN)                                                               \
  __builtin_amdgcn_s_setprio(1);                                                     \
  _Pragma("unroll") for (int mi = 0; mi < 4; mi++)                                   \
  _Pragma("unroll") for (int ni = 0; ni < 2; ni++) {                                 \
    acc[(QM) * 4 + mi][(QN) * 2 + ni] =                                              \
        MFMA16(afr[mi][0], bfr[QN][ni][0], acc[(QM) * 4 + mi][(QN) * 2 + ni]);       \
    acc[(QM) * 4 + mi][(QN) * 2 + ni] =                                              \
        MFMA16(afr[mi][1], bfr[QN][ni][1], acc[(QM) * 4 + mi][(QN) * 2 + ni]);       \
  }                                                                                  \
  __builtin_amdgcn_s_setprio(0);

#define SCHED0 __builtin_amdgcn_sched_barrier(0)

#define TILE_BODY(T, C) {                                                            \
    const int tn1 = ((T) + 1 < NTILES) ? (T) + 1 : NTILES - 1;                       \
    const int tn2 = ((T) + 2 < NTILES) ? (T) + 2 : NTILES - 1;                       \
    LDFRAG_A(C, 0); LDFRAG_B(C, 0);                                                  \
    STAGE_B(tn1, (C) ^ 1, 2); STAGE_B(tn1, (C) ^ 1, 3);                              \
    SCHED0;                                                                          \
    __builtin_amdgcn_s_barrier();                                                    \
    asm volatile("s_waitcnt lgkmcnt(0)");                                            \
    SCHED0;                                                                          \
    DOMFMA(0, 0);                                                                    \
    asm volatile("s_waitcnt vmcnt(6)" ::: "memory");                                 \
    __builtin_amdgcn_s_barrier();                                                    \
    LDFRAG_B(C, 1);                                                                  \
    STAGE_A(tn1, (C) ^ 1, 2); STAGE_A(tn1, (C) ^ 1, 3);                              \
    SCHED0;                                                                          \
    __builtin_amdgcn_s_barrier();                                                    \
    asm volatile("s_waitcnt lgkmcnt(0)");                                            \
    SCHED0;                                                                          \
    DOMFMA(0, 1);                                                                    \
    __builtin_amdgcn_s_barrier();                                                    \
    LDFRAG_A(C, 1);                                                                  \
    STAGE_A(tn2, (C), 0); STAGE_A(tn2, (C), 1);                                      \
    SCHED0;                                                                          \
    __builtin_amdgcn_s_barrier();                                                    \
    asm volatile("s_waitcnt lgkmcnt(0)");                                            \
    SCHED0;                                                                          \
    DOMFMA(1, 0);                                                                    \
    __builtin_amdgcn_s_barrier();                                                    \
    STAGE_B(tn2, (C), 0); STAGE_B(tn2, (C), 1);                                      \
    SCHED0;                                                                          \
    __builtin_amdgcn_s_barrier();                                                    \
    DOMFMA(1, 1);                                                                    \
    asm volatile("s_waitcnt vmcnt(8)" ::: "memory");                                 \
    __builtin_amdgcn_s_barrier();                                                    \
  }

  f32x4 acc[8][4];
  f32x4 zf = { 0.f, 0.f, 0.f, 0.f };
#pragma unroll
  for (int i = 0; i < 8; i++)
#pragma unroll
    for (int j = 0; j < 4; j++) acc[i][j] = zf;

  STAGE_A(0, 0, 0); STAGE_A(0, 0, 1); STAGE_A(0, 0, 2); STAGE_A(0, 0, 3);
  STAGE_B(0, 0, 0); STAGE_B(0, 0, 1); STAGE_B(0, 0, 2); STAGE_B(0, 0, 3);
  STAGE_A(1, 1, 0); STAGE_A(1, 1, 1);
  STAGE_B(1, 1, 0); STAGE_B(1, 1, 1);
  asm volatile("s_waitcnt vmcnt(4)" ::: "memory");
  __builtin_amdgcn_s_barrier();

#pragma unroll 1
  for (int tp = 0; tp < NTILES / 2; ++tp) {
    TILE_BODY(2 * tp, 0)
    TILE_BODY(2 * tp + 1, 1)
  }
  asm volatile("s_waitcnt vmcnt(0)" ::: "memory");

  // epilogue: bf16 partial (no bias) at SORTED row grow
  unsigned short* dst = blockIdx.z ? pk1 : pk0;
#pragma unroll
  for (int mi8 = 0; mi8 < 8; mi8++) {
#pragma unroll
    for (int nj = 0; nj < 4; nj++) {
#pragma unroll
      for (int r2 = 0; r2 < 4; r2++) {
        int grow = m0 + wm * 64 + (mi8 >> 2) * 128 + (mi8 & 3) * 16 + lg * 4 + r2;
        int gcol = n0 + wn * 32 + (nj >> 1) * 128 + (nj & 1) * 16 + lr;
        dst[(size_t)grow * OD_ + gcol] = f2bf(acc[mi8][nj][r2]);
      }
    }
  }
#undef STAGE_A
#undef STAGE_B
#undef LDFRAG_A
#undef LDFRAG_B
#undef DOMFMA
#undef SCHED0
#undef TILE_BODY
}

// ---------------- LN2 over 2048 -> k (head-major bf16), v (row-major bf16) ------
__global__ __launch_bounds__(256) void ln2_kernel(const unsigned short* __restrict__ kv,
    const float* __restrict__ w, const float* __restrict__ b,
    unsigned short* __restrict__ kb, unsigned short* __restrict__ vrm) {
  int wave = threadIdx.x >> 6, lane = threadIdx.x & 63;
  int t = blockIdx.x * 4 + wave;
  const unsigned short* p = kv + (size_t)t * OD_;
  float vals[4][8];
  float s = 0.f, s2 = 0.f;
#pragma unroll
  for (int i = 0; i < 4; i++) {
    short8 v = *(const short8*)(p + i * 512 + lane * 8);
#pragma unroll
    for (int j = 0; j < 8; j++) {
      float f = bf2f((unsigned short)v[j]);
      vals[i][j] = f; s += f; s2 += f * f;
    }
  }
#pragma unroll
  for (int o = 1; o < 64; o <<= 1) { s += __shfl_xor(s, o); s2 += __shfl_xor(s2, o); }
  float mu = s * (1.f / 2048.f);
  float rs = rsqrtf(s2 * (1.f / 2048.f) - mu * mu + 1e-5f);
  int bidx = t >> 10, n = t & 1023;
#pragma unroll
  for (int i = 0; i < 4; i++) {
    int c0 = i * 512 + lane * 8;
    short8 o8;
#pragma unroll
    for (int j = 0; j < 8; j++) {
      int c = c0 + j;
      o8[j] = (short)f2bf((vals[i][j] - mu) * rs * w[c] + b[c]);
    }
    if (c0 < 1024) {
      int h = c0 >> 6, d = c0 & 63;
      *(short8*)(kb + (((size_t)(bidx * 16 + h) * 1024 + n) << 6) + d) = o8;
    } else {
      *(short8*)(vrm + (size_t)t * 1024 + (c0 - 1024)) = o8;
    }
  }
}

// ---------------- V transpose: [b,n,h*64+d] -> [b,h,d,n] ----------------
__global__ __launch_bounds__(256) void transpose_v(const unsigned short* __restrict__ vrm,
                                                   unsigned short* __restrict__ vt) {
  int bh = blockIdx.x >> 4;
  int nblk = (blockIdx.x & 15) * 64;
  int b = bh >> 4, h = bh & 15;
  __shared__ unsigned short tile[64][65];
  int tid = threadIdx.x;
  int i = tid >> 2;
  int d0 = (tid & 3) * 16;
  const unsigned short* src = vrm + ((size_t)(b * 1024 + nblk + i)) * 1024 + h * 64 + d0;
  short8 v0 = *(const short8*)(src);
  short8 v1 = *(const short8*)(src + 8);
#pragma unroll
  for (int j = 0; j < 8; j++) {
    tile[d0 + j][i] = (unsigned short)v0[j];
    tile[d0 + 8 + j][i] = (unsigned short)v1[j];
  }
  __syncthreads();
  int d = tid >> 2;
  int i0 = (tid & 3) * 16;
  unsigned short* dst = vt + ((size_t)bh * 64 + d) * 1024 + nblk + i0;
  short8 o0, o1;
#pragma unroll
  for (int j = 0; j < 8; j++) { o0[j] = (short)tile[d][i0 + j]; o1[j] = (short)tile[d][i0 + 8 + j]; }
  *(short8*)dst = o0;
  *(short8*)(dst + 8) = o1;
}

// ---- flash attention: 256 thr / 4 waves, wave-private swizzled P, defer-max
// ---- (skip-max fast path), register-pipelined K/V (counted vmcnt),
// ---- XCD-affine block map; exp2-domain softmax; LAZY l-reduction:
// ---- per-lane partial l accumulated in-loop, single 16-lane reduce at end
// ---- (valid because m is uniform within each 16-lane row-group after the
// ----  max reduce, so the rescale factor al is lane-uniform).
__global__ __launch_bounds__(256) void attn_kernel(const unsigned short* __restrict__ q,
    const unsigned short* __restrict__ k, const unsigned short* __restrict__ vt,
    unsigned short* __restrict__ concat) {
  int bid = blockIdx.x;
  int bh = (bid & 7) + 8 * ((bid >> 3) & 15);      // bh%8 == bid%8 -> XCD affinity
  int wv = threadIdx.x >> 6;
  int q0 = ((bid >> 7) & 7) * 128 + wv * 32;
  int lane = threadIdx.x & 63;
  int lg = lane >> 4, lr = lane & 15;
  __shared__ unsigned short plds[4][2][512];
  unsigned short* pw = &plds[wv][0][0];
  const unsigned short* qp = q + (size_t)bh * (1024 * 64);
  const unsigned short* kp = k + (size_t)bh * (1024 * 64);
  const unsigned short* vp = vt + (size_t)bh * (64 * 1024);
  short8 qf[2][2];
#pragma unroll
  for (int rb = 0; rb < 2; rb++)
#pragma unroll
    for (int c = 0; c < 2; c++)
      qf[rb][c] = *(const short8*)(qp + (q0 + rb * 16 + lr) * 64 + c * 32 + lg * 8);
  f32x4 zf = { 0.f, 0.f, 0.f, 0.f };
  f32x4 o[2][4];
  float m[2][4], l[2][4];
#pragma unroll
  for (int rb = 0; rb < 2; rb++) {
#pragma unroll
    for (int r = 0; r < 4; r++) { m[rb][r] = -1e30f; l[rb][r] = 0.f; }
#pragma unroll
    for (int nb = 0; nb < 4; nb++) o[rb][nb] = zf;
  }
  const int prd = lr * 32 + (((lg + lr) & 3) << 3);
  // loop-invariant load bases
  const unsigned short* kb0 = kp + (size_t)lr * 64 + lg * 8;          // h2=0 rows
  const unsigned short* kb1 = kp + (size_t)(16 + lr) * 64 + lg * 8;   // h2=1 rows
  const unsigned short* vb0 = vp + (size_t)(lr) * 1024 + lg * 8;
  const unsigned short* vb1 = vp + (size_t)(16 + lr) * 1024 + lg * 8;
  const unsigned short* vb2 = vp + (size_t)(32 + lr) * 1024 + lg * 8;
  const unsigned short* vb3 = vp + (size_t)(48 + lr) * 1024 + lg * 8;

  short8 kc0, kc1, kc2, kc3;   // K(t)
  short8 vc0, vc1, vc2, vc3;   // V(t)
  // prologue: issue K(0)
  kc0 = *(const short8*)(kb0);
  kc1 = *(const short8*)(kb0 + 32);
  kc2 = *(const short8*)(kb1);
  kc3 = *(const short8*)(kb1 + 32);

#pragma unroll 1
  for (int kt = 0; kt < 1024; kt += 32) {
    // issue V(kt) — cover = QK + softmax
    vc0 = *(const short8*)(vb0 + kt);
    vc1 = *(const short8*)(vb1 + kt);
    vc2 = *(const short8*)(vb2 + kt);
    vc3 = *(const short8*)(vb3 + kt);
    asm volatile("s_waitcnt vmcnt(4)" ::: "memory");   // K(kt) landed (oldest 4)
    f32x4 s[2][2];
    s[0][0] = zf; s[0][1] = zf; s[1][0] = zf; s[1][1] = zf;
    __builtin_amdgcn_s_setprio(1);
    s[0][0] = MFMA16(qf[0][0], kc0, s[0][0]);
    s[0][0] = MFMA16(qf[0][1], kc1, s[0][0]);
    s[1][0] = MFMA16(qf[1][0], kc0, s[1][0]);
    s[1][0] = MFMA16(qf[1][1], kc1, s[1][0]);
    s[0][1] = MFMA16(qf[0][0], kc2, s[0][1]);
    s[0][1] = MFMA16(qf[0][1], kc3, s[0][1]);
    s[1][1] = MFMA16(qf[1][0], kc2, s[1][1]);
    s[1][1] = MFMA16(qf[1][1], kc3, s[1][1]);
    __builtin_amdgcn_s_setprio(0);
    // issue K(kt+32) — cover = softmax + P-trip + PV (~full tile)
    {
      const size_t ktn = (kt + 32 < 1024) ? (size_t)(kt + 32) : (size_t)kt;
      kc0 = *(const short8*)(kb0 + ktn * 64);
      kc1 = *(const short8*)(kb0 + ktn * 64 + 32);
      kc2 = *(const short8*)(kb1 + ktn * 64);
      kc3 = *(const short8*)(kb1 + ktn * 64 + 32);
    }
#pragma unroll
    for (int rb = 0; rb < 2; rb++) {
      float lmax[4];
#pragma unroll
      for (int r = 0; r < 4; r++) lmax[r] = fmaxf(s[rb][0][r], s[rb][1][r]);
      // defer-max in exp2 domain: threshold 8*log2e = 11.5416 (P bound e^8)
      bool loc = false;
#pragma unroll
      for (int r = 0; r < 4; r++) loc |= (lmax[r] > m[rb][r] + 11.5416f);
      if (__ballot(loc) != 0ull) {
        float mx[4];
#pragma unroll
        for (int r = 0; r < 4; r++) mx[r] = lmax[r];
#pragma unroll
        for (int ofs = 1; ofs < 16; ofs <<= 1)
#pragma unroll
          for (int r = 0; r < 4; r++) mx[r] = fmaxf(mx[r], __shfl_xor(mx[r], ofs));
#pragma unroll
        for (int r = 0; r < 4; r++) {
          float mn = fmaxf(m[rb][r], mx[r]);
          float al = exp2f(m[rb][r] - mn);       // lane-uniform within row-group
          m[rb][r] = mn;
          l[rb][r] *= al;
#pragma unroll
          for (int nb = 0; nb < 4; nb++) o[rb][nb][r] *= al;
        }
      }
#pragma unroll
      for (int r = 0; r < 4; r++) {
        float p0 = exp2f(s[rb][0][r] - m[rb][r]);
        float p1 = exp2f(s[rb][1][r] - m[rb][r]);
        int q_ = lg * 4 + r;
        pw[rb * 512 + q_ * 32 + ((((lr >> 3) + q_) & 3) << 3) + (lr & 7)] = f2bf(p0);
        pw[rb * 512 + q_ * 32 + (((2 + (lr >> 3) + q_) & 3) << 3) + (lr & 7)] = f2bf(p1);
        l[rb][r] += p0 + p1;                     // per-lane partial; reduce at end
      }
    }
    asm volatile("s_waitcnt lgkmcnt(0)" ::: "memory");   // own P writes complete
    short8 pf0 = *(const short8*)(pw + prd);
    short8 pf1 = *(const short8*)(pw + 512 + prd);
    asm volatile("s_waitcnt vmcnt(4)" ::: "memory");   // V(kt) landed; K(kt+32) in flight
    __builtin_amdgcn_s_setprio(1);
    o[0][0] = MFMA16(pf0, vc0, o[0][0]);
    o[1][0] = MFMA16(pf1, vc0, o[1][0]);
    o[0][1] = MFMA16(pf0, vc1, o[0][1]);
    o[1][1] = MFMA16(pf1, vc1, o[1][1]);
    o[0][2] = MFMA16(pf0, vc2, o[0][2]);
    o[1][2] = MFMA16(pf1, vc2, o[1][2]);
    o[0][3] = MFMA16(pf0, vc3, o[0][3]);
    o[1][3] = MFMA16(pf1, vc3, o[1][3]);
    __builtin_amdgcn_s_setprio(0);
  }
  // one-time l reduction across the 16-lane row-group (was per-tile)
#pragma unroll
  for (int ofs = 1; ofs < 16; ofs <<= 1)
#pragma unroll
    for (int rb = 0; rb < 2; rb++)
#pragma unroll
      for (int r = 0; r < 4; r++) l[rb][r] += __shfl_xor(l[rb][r], ofs);
  int b = bh >> 4, h = bh & 15;
#pragma unroll
  for (int rb = 0; rb < 2; rb++)
#pragma unroll
    for (int r = 0; r < 4; r++) {
      int n = q0 + rb * 16 + lg * 4 + r;
      size_t t = (size_t)b * 1024 + n;       // ORIGINAL token row
      float inv = 1.f / l[rb][r];
#pragma unroll
      for (int nb = 0; nb < 4; nb++)
        concat[t * CD_ + 4096 + h * 64 + nb * 16 + lr] = f2bf(o[rb][nb][r] * inv);
    }
}

// -------- final epilogue: split-K reduce + cbias + mask + residual + combine ----
// loads skipped for masked columns (dout is 4-aligned per thread quad)
__global__ __launch_bounds__(256) void final_epi(const unsigned short* __restrict__ p0,
    const unsigned short* __restrict__ p1, const float* __restrict__ cbias,
    const float* __restrict__ x, const float* __restrict__ probs,
    const int* __restrict__ emask, const int* __restrict__ pos,
    float* __restrict__ out) {
  int t = blockIdx.x;
  int c = threadIdx.x * 4;
  int dout = 2048 >> (3 - emask[t]);
  float p = probs[t];
  size_t row = (size_t)pos[t] * OD_;
  ushort4_t zz = { 0, 0, 0, 0 };
  ushort4_t m0v = zz, m1v = zz, a0v = zz, a1v = zz;
  if (c < dout) {
    m0v = *(const ushort4_t*)(p0 + row + c);
    m1v = *(const ushort4_t*)(p1 + row + c);
  }
  if (1024 + c < dout) {
    a0v = *(const ushort4_t*)(p0 + row + 1024 + c);
    a1v = *(const ushort4_t*)(p1 + row + 1024 + c);
  }
  float4 xv = *(const float4*)(x + (size_t)t * 1024 + c);
  float xa[4] = { xv.x, xv.y, xv.z, xv.w };
  float4 o;
  float oa[4];
#pragma unroll
  for (int j = 0; j < 4; j++) {
    float mlp = ((c + j) < dout ? bf2f(m0v[j]) + bf2f(m1v[j]) + cbias[c + j] : 0.f) + xa[j];
    float att = ((1024 + c + j) < dout ?
                 bf2f(a0v[j]) + bf2f(a1v[j]) + cbias[1024 + c + j] : 0.f) + xa[j];
    oa[j] = att + p * mlp;
  }
  o.x = oa[0]; o.y = oa[1]; o.z = oa[2]; o.w = oa[3];
  *(float4*)(out + (size_t)t * 1024 + c) = o;
}

extern "C" void kernel_launch(void* const* d_in, const int* in_sizes, int n_in,
                              void* d_out, int out_size, void* d_ws, size_t ws_size,
                              hipStream_t stream) {
  const float* x        = (const float*)d_in[0];
  const float* probs    = (const float*)d_in[1];
  const float* we       = (const float*)d_in[2];
  const float* mlp_bias = (const float*)d_in[3];
  const float* wc       = (const float*)d_in[4];
  const float* cbias    = (const float*)d_in[5];
  const float* n1w      = (const float*)d_in[6];
  const float* n1b      = (const float*)d_in[7];
  const float* n2w      = (const float*)d_in[8];
  const float* n2b      = (const float*)d_in[9];
  const int*   emask    = (const int*)d_in[10];
  float* out = (float*)d_out;

  char* ws = (char*)d_ws;
  size_t off = 0;
  auto alloc = [&](size_t bytes) {
    char* p = ws + off;
    off += (bytes + 255) & ~(size_t)255;
    return p;
  };
  unsigned short* we_bf = (unsigned short*)alloc((size_t)EXP_ * DIM_ * 2);
  unsigned short* wc_bf = (unsigned short*)alloc((size_t)OD_ * CD_ * 2);
  unsigned short* xn    = (unsigned short*)alloc((size_t)MPAD * DIM_ * 2); // sorted; reused as vrm
  unsigned short* qb    = (unsigned short*)alloc((size_t)NT * DIM_ * 2);
  unsigned short* kv    = (unsigned short*)alloc((size_t)NT * OD_ * 2);    // orig order
  unsigned short* kb    = (unsigned short*)alloc((size_t)NT * DIM_ * 2);
  unsigned short* vt    = (unsigned short*)alloc((size_t)NT * DIM_ * 2);
  unsigned short* cc    = (unsigned short*)alloc((size_t)NT * CD_ * 2);    // ORIGINAL order
  int* blockCnt         = (int*)alloc(32 * 4 * 4);
  int* desc             = (int*)alloc(256 * 4);
  int* perm             = (int*)alloc(MPAD * 4);
  int* pos              = (int*)alloc(NT * 4);
  unsigned short* vrm = xn;
  // split-K partials overlay xn..kb region (all dead after attn):
  // need 2 x MPAD*OD_*2 = 71.3 MB of the ~85 MB span. cc untouched.
  unsigned short* pk0 = xn;
  unsigned short* pk1 = xn + (size_t)MPAD * OD_;
  if (off > ws_size) return;  // insufficient workspace -> visible failure, no OOB

  // allow 128 KiB dynamic LDS for the 8-phase GEMM2 (host-side, not captured)
  hipFuncSetAttribute((const void*)gemm2_8p,
                      hipFuncAttributeMaxDynamicSharedMemorySize, 131072);

  count_experts<<<32, 256, 0, stream>>>(emask, blockCnt);
  scan_make<<<1, 64, 0, stream>>>(blockCnt, desc);
  fill_perm<<<34, 256, 0, stream>>>(perm);
  scatter_perm<<<32, 256, 0, stream>>>(emask, desc, perm, pos);

  cvt_bf16<<<7168, 256, 0, stream>>>(we, we_bf, EXP_ * DIM_);
  cvt_bf16<<<10240, 256, 0, stream>>>(wc, wc_bf, OD_ * CD_);
  ln1_kernel<<<2048, 256, 0, stream>>>(x, n1w, n1b, emask, pos, xn);
  gemm_grp1<<<dim3(56, NRT), 256, 0, stream>>>(xn, we_bf, mlp_bias, desc,
                                               perm, qb, kv, cc);
  ln2_kernel<<<2048, 256, 0, stream>>>(kv, n2w, n2b, kb, vrm);
  transpose_v<<<2048, 256, 0, stream>>>(vrm, vt);
  attn_kernel<<<1024, 256, 0, stream>>>(qb, kb, vt, cc);
  gemm2_8p<<<dim3(8, 34, 2), 512, 131072, stream>>>(cc, wc_bf, desc, perm, pk0, pk1);
  final_epi<<<8192, 256, 0, stream>>>(pk0, pk1, cbias, x, probs, emask, pos, out);
}

// Round 23
// 460.928 us; speedup vs baseline: 1.0083x; 1.0083x over previous
//
#include <hip/hip_runtime.h>
#include <cmath>

#define NT    8192      // B*N tokens
#define DIM_  1024
#define EXP_  7168
#define CD_   5120      // concat dim (4096 mlp + 1024 attn)
#define OD_   2048
#define MPAD  8704      // 68 row-tiles of 128 (8192 + worst-case group padding)
#define NRT   68        // row tiles (128) in sorted/padded space

typedef __attribute__((ext_vector_type(8))) short short8;
typedef __attribute__((ext_vector_type(4))) float f32x4;
typedef __attribute__((ext_vector_type(4))) unsigned short ushort4_t;

__device__ __forceinline__ unsigned short f2bf(float f) {
  union { float f; unsigned u; } v; v.f = f;
  return (unsigned short)((v.u + 0x7FFFu + ((v.u >> 16) & 1u)) >> 16);
}
// truncating bf16 (1 op); used only for P in attn (bounded [0,1], error <=0.4% rel)
__device__ __forceinline__ unsigned short f2bf_t(float f) {
  union { float f; unsigned u; } v; v.f = f;
  return (unsigned short)(v.u >> 16);
}
__device__ __forceinline__ float bf2f(unsigned short u) {
  union { unsigned u; float f; } v; v.u = ((unsigned)u) << 16;
  return v.f;
}
// tanh-form GELU (|err| vs exact erf-GELU < 1e-3); exp + hw rcp, ~9 VALU ops
__device__ __forceinline__ float fast_gelu(float x) {
  float y = 1.5957691216f * (x + 0.044715f * x * x * x);   // 2 * 0.79788456 * (...)
  float e = __expf(y);
  float t = 1.f - 2.f * __builtin_amdgcn_rcpf(1.f + e);    // tanh(y/2)
  return 0.5f * x * (1.f + t);
}

#define MFMA16(a, b, c) __builtin_amdgcn_mfma_f32_16x16x32_bf16(a, b, c, 0, 0, 0)

// ======== expert sort (128-granular): count -> scan -> fill -> scatter ========
__global__ __launch_bounds__(256) void count_experts(const int* __restrict__ em,
                                                     int* __restrict__ blockCnt) {
  __shared__ int h[4];
  int tid = threadIdx.x;
  if (tid < 4) h[tid] = 0;
  __syncthreads();
  atomicAdd(&h[em[blockIdx.x * 256 + tid]], 1);
  __syncthreads();
  if (tid < 4) blockCnt[blockIdx.x * 4 + tid] = h[tid];
}

__global__ void scan_make(const int* __restrict__ blockCnt, int* __restrict__ desc) {
  if (threadIdx.x != 0) return;
  int cnt[4] = {0, 0, 0, 0};
  for (int b = 0; b < 32; b++)
    for (int e = 0; e < 4; e++) cnt[e] += blockCnt[b * 4 + e];
  int base[4]; int acc = 0;
  for (int e = 0; e < 4; e++) { base[e] = acc; acc += ((cnt[e] + 127) >> 7) << 7; }
  for (int e = 0; e < 4; e++) { desc[e] = base[e]; desc[4 + e] = cnt[e]; }
  for (int r = 0; r < NRT; r++) {
    int te = -1;
    for (int e = 0; e < 4; e++) {
      int lo = base[e] >> 7;
      int hi = (base[e] + (((cnt[e] + 127) >> 7) << 7)) >> 7;
      if (r >= lo && r < hi) te = e;
    }
    desc[8 + r] = te;
  }
  int run[4];
  for (int e = 0; e < 4; e++) run[e] = base[e];
  for (int b = 0; b < 32; b++)
    for (int e = 0; e < 4; e++) { desc[76 + b * 4 + e] = run[e]; run[e] += blockCnt[b * 4 + e]; }
}

__global__ __launch_bounds__(256) void fill_perm(int* __restrict__ perm) {
  int i = blockIdx.x * 256 + threadIdx.x;
  if (i < MPAD) perm[i] = -1;
}

__global__ __launch_bounds__(256) void scatter_perm(const int* __restrict__ em,
    const int* __restrict__ desc, int* __restrict__ perm, int* __restrict__ pos) {
  __shared__ int wsum[4][4];
  int tid = threadIdx.x;
  int wv = tid >> 6, ln = tid & 63;
  int t = blockIdx.x * 256 + tid;
  int e = em[t];
  int wrank = 0;
#pragma unroll
  for (int k = 0; k < 4; k++) {
    unsigned long long m = __ballot(e == k);
    if (ln == 0) wsum[wv][k] = __popcll(m);
    if (e == k) wrank = __popcll(m & ((1ull << ln) - 1ull));
  }
  __syncthreads();
  int off = desc[76 + blockIdx.x * 4 + e];
  for (int w = 0; w < wv; w++) off += wsum[w][e];
  int p = off + wrank;
  perm[p] = t;
  pos[t] = p;
}

// ---------------- fp32 -> bf16 convert ----------------
__global__ __launch_bounds__(256) void cvt_bf16(const float* __restrict__ in,
                                                unsigned short* __restrict__ out, int n) {
  int i = (blockIdx.x * 256 + threadIdx.x) * 4;
  if (i >= n) return;
  float4 v = *(const float4*)(in + i);
  ushort4_t o;
  o[0] = f2bf(v.x); o[1] = f2bf(v.y); o[2] = f2bf(v.z); o[3] = f2bf(v.w);
  *(ushort4_t*)(out + i) = o;
}

// ---------------- LN1 + expert input mask -> xn bf16 (SORTED rows) ---------------
__global__ __launch_bounds__(256) void ln1_kernel(const float* __restrict__ x,
    const float* __restrict__ w, const float* __restrict__ b,
    const int* __restrict__ emask, const int* __restrict__ pos,
    unsigned short* __restrict__ xn) {
  int wave = threadIdx.x >> 6, lane = threadIdx.x & 63;
  int t = blockIdx.x * 4 + wave;
  const float* xt = x + (size_t)t * DIM_;
  float4 v[4];
  float s = 0.f, s2 = 0.f;
#pragma unroll
  for (int i = 0; i < 4; i++) {
    v[i] = *(const float4*)(xt + i * 256 + lane * 4);
    s  += v[i].x + v[i].y + v[i].z + v[i].w;
    s2 += v[i].x * v[i].x + v[i].y * v[i].y + v[i].z * v[i].z + v[i].w * v[i].w;
  }
#pragma unroll
  for (int o = 1; o < 64; o <<= 1) { s += __shfl_xor(s, o); s2 += __shfl_xor(s2, o); }
  float mu = s * (1.f / 1024.f);
  float rs = rsqrtf(s2 * (1.f / 1024.f) - mu * mu + 1e-5f);
  int din = 1024 >> (3 - emask[t]);
  unsigned short* ot = xn + (size_t)pos[t] * DIM_;
#pragma unroll
  for (int i = 0; i < 4; i++) {
    int c0 = i * 256 + lane * 4;
    float fv[4] = { v[i].x, v[i].y, v[i].z, v[i].w };
    ushort4_t o;
#pragma unroll
    for (int j = 0; j < 4; j++) {
      int c = c0 + j;
      float val = (c < din) ? (fv[j] - mu) * rs * w[c] + b[c] : 0.f;
      o[j] = f2bf(val);
    }
    *(ushort4_t*)(ot + c0) = o;
  }
}

// ---- GEMM1: grouped 128x128 bf16, 2-slot double buffer, 3 blocks/CU (R7) -------
// K = 128<<e per row-tile; epilogue scatters q/kv/cc to ORIGINAL token rows.
// q is pre-scaled by 0.125*log2(e) so attention softmax runs in exp2 domain.
__global__ __launch_bounds__(256, 3) void gemm_grp1(
    const unsigned short* __restrict__ A, const unsigned short* __restrict__ W,
    const float* __restrict__ bias, const int* __restrict__ tdesc,
    const int* __restrict__ perm, unsigned short* __restrict__ out0,
    unsigned short* __restrict__ out1, unsigned short* __restrict__ out2) {
  __shared__ unsigned short lds[16384];          // 32 KiB: As[2][4096] | Bs[2][4096]
  unsigned short* As = lds;
  unsigned short* Bs = lds + 8192;
  const int r = blockIdx.y;
  const int e = tdesc[8 + r];
  if (e < 0) return;                             // pad tile (uniform exit)
  const int ntiles = 4 << e;                     // K = 128<<e, BK=32
  constexpr int KK = 1024;

  const int tid = threadIdx.x;
  const int lane = tid & 63;
  const int wave = tid >> 6;       // 0..3
  const int wm = wave >> 1, wn = wave & 1;
  const int lg = lane >> 4, lr = lane & 15;

  // XCD swizzle on col dim (56 % 8 == 0)
  constexpr int CPX = 56 >> 3;
  const int bx = (int)blockIdx.x;
  const int bn = (bx & 7) * CPX + (bx >> 3);
  const int n0 = bn * 128;
  const int m0 = r * 128;

  // staging source map (inverse of superrow XOR swizzle)
  const int s0g = tid >> 3,        s1g = (256 + tid) >> 3;
  const int lc0 = (tid & 7) ^ (s0g & 7), lc1 = (tid & 7) ^ (s1g & 7);
  const int row0 = 2 * s0g + (lc0 >> 2), kc0 = lc0 & 3;
  const int row1 = 2 * s1g + (lc1 >> 2), kc1 = lc1 & 3;
  const unsigned short* aS0 = A + (size_t)(m0 + row0) * KK + kc0 * 8;
  const unsigned short* aS1 = A + (size_t)(m0 + row1) * KK + kc1 * 8;
  const unsigned short* bS0 = W + (size_t)(n0 + row0) * KK + kc0 * 8;
  const unsigned short* bS1 = W + (size_t)(n0 + row1) * KK + kc1 * 8;

#define GLD(SRC, DST)                                                                \
  __builtin_amdgcn_global_load_lds(                                                  \
      (const __attribute__((address_space(1))) void*)(SRC),                          \
      (__attribute__((address_space(3))) void*)(DST), 16, 0, 0)
#define STAGE(T, SLOT) {                                                             \
    GLD(aS0 + (size_t)(T) * 32, As + (SLOT) * 4096 + tid * 8);                       \
    GLD(aS1 + (size_t)(T) * 32, As + (SLOT) * 4096 + 2048 + tid * 8);                \
    GLD(bS0 + (size_t)(T) * 32, Bs + (SLOT) * 4096 + tid * 8);                       \
    GLD(bS1 + (size_t)(T) * 32, Bs + (SLOT) * 4096 + 2048 + tid * 8);                \
  }

  const int fb = (lr >> 1) * 128 + ((((lr & 1) << 2) + lg) ^ ((lr >> 1) & 7)) * 16;
  const char* apb = (const char*)As + wm * 4096 + fb;
  const char* bpb = (const char*)Bs + wn * 4096 + fb;

  short8 afr[4], bfr[4];
#define LDFRAG(C)                                                                    \
  _Pragma("unroll") for (int mi = 0; mi < 4; mi++)                                   \
    afr[mi] = *(const short8*)(apb + (C) * 8192 + mi * 1024);                        \
  _Pragma("unroll") for (int ni = 0; ni < 4; ni++)                                   \
    bfr[ni] = *(const short8*)(bpb + (C) * 8192 + ni * 1024);

  f32x4 acc[4][4];
  f32x4 zf = { 0.f, 0.f, 0.f, 0.f };
#pragma unroll
  for (int i = 0; i < 4; i++)
#pragma unroll
    for (int j = 0; j < 4; j++) acc[i][j] = zf;

  STAGE(0, 0)
  STAGE(1, 1)
  asm volatile("s_waitcnt vmcnt(4)" ::: "memory");
  __builtin_amdgcn_s_barrier();

#pragma unroll 1
  for (int t = 0; t < ntiles; ++t) {
    const int c = t & 1;
    LDFRAG(c)
    asm volatile("s_waitcnt lgkmcnt(0)" ::: "memory");
    __builtin_amdgcn_sched_barrier(0);
    __builtin_amdgcn_s_barrier();
    const int t2 = (t + 2 < ntiles) ? t + 2 : t;
    STAGE(t2, c)
    __builtin_amdgcn_s_setprio(1);
#pragma unroll
    for (int mi = 0; mi < 4; mi++)
#pragma unroll
      for (int ni = 0; ni < 4; ni++)
        acc[mi][ni] = MFMA16(afr[mi], bfr[ni], acc[mi][ni]);
    __builtin_amdgcn_s_setprio(0);
    asm volatile("s_waitcnt vmcnt(4)" ::: "memory");
    __builtin_amdgcn_s_barrier();
  }
  asm volatile("s_waitcnt vmcnt(0)" ::: "memory");

  // epilogue: grow (sorted) = m0+wm*64+mi*16+lg*4+rr ; gcol = n0w+ni*16+lr
  // region is uniform per wave (64-col slice, boundaries 64-aligned)
  const int n0w = n0 + wn * 64;
  auto epi_loop = [&](auto&& body) {
#pragma unroll
    for (int mi = 0; mi < 4; mi++)
#pragma unroll
      for (int ni = 0; ni < 4; ni++)
#pragma unroll
        for (int rr = 0; rr < 4; rr++) {
          int grow = m0 + wm * 64 + mi * 16 + lg * 4 + rr;
          int tk = perm[grow];
          int gcol = n0w + ni * 16 + lr;
          body(tk, gcol, acc[mi][ni][rr]);
        }
  };
  if (n0w < 1024) {                    // q: scaled (0.125*log2e), head-major
    epi_loop([&](int tk, int gcol, float v) {
      if (tk >= 0) {
        float vv = (v + bias[gcol]) * 0.18033688f;   // 0.125 * log2(e)
        int bb = tk >> 10;
        int n = tk & 1023;
        int h = gcol >> 6;
        int d = gcol & 63;
        out0[(((size_t)(bb * 16 + h) * 1024 + n) << 6) + d] = f2bf(vv);
      }
    });
  } else if (n0w < 3072) {             // kv (pre-LN2)
    epi_loop([&](int tk, int gcol, float v) {
      if (tk >= 0) out1[(size_t)tk * OD_ + (gcol - 1024)] = f2bf(v + bias[gcol]);
    });
  } else {                             // mlp hidden -> fast gelu -> cc
    const bool hasb = (n0w < 4096);    // bias covers cols [0,4096) only
    epi_loop([&](int tk, int gcol, float v) {
      if (tk >= 0) {
        float vb = v + (hasb ? bias[gcol] : 0.f);
        out2[(size_t)tk * CD_ + (gcol - 3072)] = f2bf(fast_gelu(vb));
      }
    });
  }
#undef GLD
#undef STAGE
#undef LDFRAG
}

// ---- GEMM2: expert-sparse split-K 256x256 8-phase over SORTED rows -------------
// Row tile r = sorted rows [256r,256r+256); A-rows gathered via perm.
// Col-tiles bn >= 2^emax exit; bn rotated by r for XCD balance; split-K=2.
__global__ __launch_bounds__(512, 2) void gemm2_8p(
    const unsigned short* __restrict__ A, const unsigned short* __restrict__ W,
    const int* __restrict__ tdesc, const int* __restrict__ perm,
    unsigned short* __restrict__ pk0, unsigned short* __restrict__ pk1) {
  extern __shared__ unsigned short lds[];
  unsigned short* As = lds;            // [2 slots][16384] elems
  unsigned short* Bs = lds + 32768;
  constexpr int KK = 5120;
  constexpr int NTILES = 40;           // K half = 2560, BK=64
  const int r = blockIdx.y;            // 256-row sorted tile (34 total)
  const int ea = tdesc[8 + 2 * r];
  const int eb = tdesc[8 + 2 * r + 1];
  const int emax = (ea > eb) ? ea : eb;
  if (emax < 0) return;                // both halves pad (uniform exit)
  const int bn = ((int)blockIdx.x + r) & 7;     // rotated col-tile for XCD spread
  if (bn >= (1 << emax)) return;                // masked-out output cols
  const int k0 = (int)blockIdx.z * 2560;

  const int tid = threadIdx.x;
  const int lane = tid & 63;
  const int wave = tid >> 6;   // 0..7
  const int wm = wave >> 2;    // 0..1
  const int wn = wave & 3;     // 0..3
  const int lg = lane >> 4, lr = lane & 15;
  const int m0 = r * 256, n0 = bn * 256;

  const int srow = tid >> 3;
  const int schunk = (tid & 7) ^ (srow & 7);
  // A-row gather via perm (pad rows clamp to row 0; their outputs never gathered)
  const unsigned short* aSrcS[4];
#pragma unroll
  for (int s4 = 0; s4 < 4; s4++) {
    int tk = perm[m0 + s4 * 64 + srow];
    if (tk < 0) tk = 0;
    aSrcS[s4] = A + (size_t)tk * KK + k0 + schunk * 8;
  }
  const unsigned short* bSrc = W + (size_t)(n0 + srow) * KK + k0 + schunk * 8;

  const int xor0 = (lg ^ (lr & 7)) * 8;
  const int xor1 = ((4 + lg) ^ (lr & 7)) * 8;
  const unsigned short* ap0 = As + (wm * 64 + lr) * 64 + xor0;
  const unsigned short* ap1 = As + (wm * 64 + lr) * 64 + xor1;
  const unsigned short* bp0 = Bs + (wn * 32 + lr) * 64 + xor0;
  const unsigned short* bp1 = Bs + (wn * 32 + lr) * 64 + xor1;

#define STAGE_A(TT, SLOT, SEG)                                                       \
  __builtin_amdgcn_global_load_lds(                                                  \
    (const __attribute__((address_space(1))) void*)(aSrcS[SEG] +                     \
      (size_t)(TT) * 64),                                                            \
    (__attribute__((address_space(3))) void*)(As + (SLOT) * 16384 +                  \
      (SEG) * 4096 + tid * 8), 16, 0, 0)
#define STAGE_B(TT, SLOT, SEG)                                                       \
  __builtin_amdgcn_global_load_lds(                                                  \
    (const __attribute__((address_space(1))) void*)(bSrc +                           \
      (size_t)(SEG) * 64 * KK + (size_t)(TT) * 64),                                  \
    (__attribute__((address_space(3))) void*)(Bs + (SLOT) * 16384 +                  \
      (SEG) * 4096 + tid * 8), 16, 0, 0)

  short8 afr[4][2], bfr[2][2][2];
#define LDFRAG_A(C, QM)                                                              \
  _Pragma("unroll") for (int mi = 0; mi < 4; mi++) {                                 \
    afr[mi][0] = *(const short8*)(ap0 + (C) * 16384 + (QM) * 8192 + mi * 1024);      \
    afr[mi][1] = *(const short8*)(ap1 + (C) * 16384 + (QM) * 8192 + mi * 1024);      \
  }
#define LDFRAG_B(C, QN)                                                              \
  _Pragma("unroll") for (int ni = 0; ni < 2; ni++) {                                 \
    bfr[QN][ni][0] = *(const short8*)(bp0 + (C) * 16384 + (QN) * 8192 + ni * 1024);  \
    bfr[QN][ni][1] = *(const short8*)(bp1 + (C) * 16384 + (QN) * 8192 + ni * 1024);  \
  }
#define DOMFMA(QM, QN)                                                               \
  __builtin_amdgcn_s_setprio(1);                                                     \
  _Pragma("unroll") for (int mi = 0; mi < 4; mi++)                                   \
  _Pragma("unroll") for (int ni = 0; ni < 2; ni++) {                                 \
    acc[(QM) * 4 + mi][(QN) * 2 + ni] =                                              \
        MFMA16(afr[mi][0], bfr[QN][ni][0], acc[(QM) * 4 + mi][(QN) * 2 + ni]);       \
    acc[(QM) * 4 + mi][(QN) * 2 + ni] =                                              \
        MFMA16(afr[mi][1], bfr[QN][ni][1], acc[(QM) * 4 + mi][(QN) * 2 + ni]);       \
  }                                                                                  \
  __builtin_amdgcn_s_setprio(0);

#define SCHED0 __builtin_amdgcn_sched_barrier(0)

#define TILE_BODY(T, C) {                                                            \
    const int tn1 = ((T) + 1 < NTILES) ? (T) + 1 : NTILES - 1;                       \
    const int tn2 = ((T) + 2 < NTILES) ? (T) + 2 : NTILES - 1;                       \
    LDFRAG_A(C, 0); LDFRAG_B(C, 0);                                                  \
    STAGE_B(tn1, (C) ^ 1, 2); STAGE_B(tn1, (C) ^ 1, 3);                              \
    SCHED0;                                                                          \
    __builtin_amdgcn_s_barrier();                                                    \
    asm volatile("s_waitcnt lgkmcnt(0)");                                            \
    SCHED0;                                                                          \
    DOMFMA(0, 0);                                                                    \
    asm volatile("s_waitcnt vmcnt(6)" ::: "memory");                                 \
    __builtin_amdgcn_s_barrier();                                                    \
    LDFRAG_B(C, 1);                                                                  \
    STAGE_A(tn1, (C) ^ 1, 2); STAGE_A(tn1, (C) ^ 1, 3);                              \
    SCHED0;                                                                          \
    __builtin_amdgcn_s_barrier();                                                    \
    asm volatile("s_waitcnt lgkmcnt(0)");                                            \
    SCHED0;                                                                          \
    DOMFMA(0, 1);                                                                    \
    __builtin_amdgcn_s_barrier();                                                    \
    LDFRAG_A(C, 1);                                                                  \
    STAGE_A(tn2, (C), 0); STAGE_A(tn2, (C), 1);                                      \
    SCHED0;                                                                          \
    __builtin_amdgcn_s_barrier();                                                    \
    asm volatile("s_waitcnt lgkmcnt(0)");                                            \
    SCHED0;                                                                          \
    DOMFMA(1, 0);                                                                    \
    __builtin_amdgcn_s_barrier();                                                    \
    STAGE_B(tn2, (C), 0); STAGE_B(tn2, (C), 1);                                      \
    SCHED0;                                                                          \
    __builtin_amdgcn_s_barrier();                                                    \
    DOMFMA(1, 1);                                                                    \
    asm volatile("s_waitcnt vmcnt(8)" ::: "memory");                                 \
    __builtin_amdgcn_s_barrier();                                                    \
  }

  f32x4 acc[8][4];
  f32x4 zf = { 0.f, 0.f, 0.f, 0.f };
#pragma unroll
  for (int i = 0; i < 8; i++)
#pragma unroll
    for (int j = 0; j < 4; j++) acc[i][j] = zf;

  STAGE_A(0, 0, 0); STAGE_A(0, 0, 1); STAGE_A(0, 0, 2); STAGE_A(0, 0, 3);
  STAGE_B(0, 0, 0); STAGE_B(0, 0, 1); STAGE_B(0, 0, 2); STAGE_B(0, 0, 3);
  STAGE_A(1, 1, 0); STAGE_A(1, 1, 1);
  STAGE_B(1, 1, 0); STAGE_B(1, 1, 1);
  asm volatile("s_waitcnt vmcnt(4)" ::: "memory");
  __builtin_amdgcn_s_barrier();

#pragma unroll 1
  for (int tp = 0; tp < NTILES / 2; ++tp) {
    TILE_BODY(2 * tp, 0)
    TILE_BODY(2 * tp + 1, 1)
  }
  asm volatile("s_waitcnt vmcnt(0)" ::: "memory");

  // epilogue: bf16 partial (no bias) at SORTED row grow
  unsigned short* dst = blockIdx.z ? pk1 : pk0;
#pragma unroll
  for (int mi8 = 0; mi8 < 8; mi8++) {
#pragma unroll
    for (int nj = 0; nj < 4; nj++) {
#pragma unroll
      for (int r2 = 0; r2 < 4; r2++) {
        int grow = m0 + wm * 64 + (mi8 >> 2) * 128 + (mi8 & 3) * 16 + lg * 4 + r2;
        int gcol = n0 + wn * 32 + (nj >> 1) * 128 + (nj & 1) * 16 + lr;
        dst[(size_t)grow * OD_ + gcol] = f2bf(acc[mi8][nj][r2]);
      }
    }
  }
#undef STAGE_A
#undef STAGE_B
#undef LDFRAG_A
#undef LDFRAG_B
#undef DOMFMA
#undef SCHED0
#undef TILE_BODY
}

// ---------------- LN2 over 2048 -> k (head-major bf16), v (row-major bf16) ------
__global__ __launch_bounds__(256) void ln2_kernel(const unsigned short* __restrict__ kv,
    const float* __restrict__ w, const float* __restrict__ b,
    unsigned short* __restrict__ kb, unsigned short* __restrict__ vrm) {
  int wave = threadIdx.x >> 6, lane = threadIdx.x & 63;
  int t = blockIdx.x * 4 + wave;
  const unsigned short* p = kv + (size_t)t * OD_;
  float vals[4][8];
  float s = 0.f, s2 = 0.f;
#pragma unroll
  for (int i = 0; i < 4; i++) {
    short8 v = *(const short8*)(p + i * 512 + lane * 8);
#pragma unroll
    for (int j = 0; j < 8; j++) {
      float f = bf2f((unsigned short)v[j]);
      vals[i][j] = f; s += f; s2 += f * f;
    }
  }
#pragma unroll
  for (int o = 1; o < 64; o <<= 1) { s += __shfl_xor(s, o); s2 += __shfl_xor(s2, o); }
  float mu = s * (1.f / 2048.f);
  float rs = rsqrtf(s2 * (1.f / 2048.f) - mu * mu + 1e-5f);
  int bidx = t >> 10, n = t & 1023;
#pragma unroll
  for (int i = 0; i < 4; i++) {
    int c0 = i * 512 + lane * 8;
    short8 o8;
#pragma unroll
    for (int j = 0; j < 8; j++) {
      int c = c0 + j;
      o8[j] = (short)f2bf((vals[i][j] - mu) * rs * w[c] + b[c]);
    }
    if (c0 < 1024) {
      int h = c0 >> 6, d = c0 & 63;
      *(short8*)(kb + (((size_t)(bidx * 16 + h) * 1024 + n) << 6) + d) = o8;
    } else {
      *(short8*)(vrm + (size_t)t * 1024 + (c0 - 1024)) = o8;
    }
  }
}

// ---------------- V transpose: [b,n,h*64+d] -> [b,h,d,n] ----------------
__global__ __launch_bounds__(256) void transpose_v(const unsigned short* __restrict__ vrm,
                                                   unsigned short* __restrict__ vt) {
  int bh = blockIdx.x >> 4;
  int nblk = (blockIdx.x & 15) * 64;
  int b = bh >> 4, h = bh & 15;
  __shared__ unsigned short tile[64][65];
  int tid = threadIdx.x;
  int i = tid >> 2;
  int d0 = (tid & 3) * 16;
  const unsigned short* src = vrm + ((size_t)(b * 1024 + nblk + i)) * 1024 + h * 64 + d0;
  short8 v0 = *(const short8*)(src);
  short8 v1 = *(const short8*)(src + 8);
#pragma unroll
  for (int j = 0; j < 8; j++) {
    tile[d0 + j][i] = (unsigned short)v0[j];
    tile[d0 + 8 + j][i] = (unsigned short)v1[j];
  }
  __syncthreads();
  int d = tid >> 2;
  int i0 = (tid & 3) * 16;
  unsigned short* dst = vt + ((size_t)bh * 64 + d) * 1024 + nblk + i0;
  short8 o0, o1;
#pragma unroll
  for (int j = 0; j < 8; j++) { o0[j] = (short)tile[d][i0 + j]; o1[j] = (short)tile[d][i0 + 8 + j]; }
  *(short8*)dst = o0;
  *(short8*)(dst + 8) = o1;
}

// ---- flash attention: 256 thr / 4 waves, wave-private swizzled P, defer-max
// ---- (single fused skip gate), register-pipelined K/V (counted vmcnt),
// ---- XCD-affine block map; exp2-domain softmax; lazy l-reduction;
// ---- P stored with TRUNCATING bf16 (1 op vs 3; P in [0,1], l stays exact f32)
__global__ __launch_bounds__(256) void attn_kernel(const unsigned short* __restrict__ q,
    const unsigned short* __restrict__ k, const unsigned short* __restrict__ vt,
    unsigned short* __restrict__ concat) {
  int bid = blockIdx.x;
  int bh = (bid & 7) + 8 * ((bid >> 3) & 15);      // bh%8 == bid%8 -> XCD affinity
  int wv = threadIdx.x >> 6;
  int q0 = ((bid >> 7) & 7) * 128 + wv * 32;
  int lane = threadIdx.x & 63;
  int lg = lane >> 4, lr = lane & 15;
  __shared__ unsigned short plds[4][2][512];
  unsigned short* pw = &plds[wv][0][0];
  const unsigned short* qp = q + (size_t)bh * (1024 * 64);
  const unsigned short* kp = k + (size_t)bh * (1024 * 64);
  const unsigned short* vp = vt + (size_t)bh * (64 * 1024);
  short8 qf[2][2];
#pragma unroll
  for (int rb = 0; rb < 2; rb++)
#pragma unroll
    for (int c = 0; c < 2; c++)
      qf[rb][c] = *(const short8*)(qp + (q0 + rb * 16 + lr) * 64 + c * 32 + lg * 8);
  f32x4 zf = { 0.f, 0.f, 0.f, 0.f };
  f32x4 o[2][4];
  float m[2][4], l[2][4];
#pragma unroll
  for (int rb = 0; rb < 2; rb++) {
#pragma unroll
    for (int r = 0; r < 4; r++) { m[rb][r] = -1e30f; l[rb][r] = 0.f; }
#pragma unroll
    for (int nb = 0; nb < 4; nb++) o[rb][nb] = zf;
  }
  const int prd = lr * 32 + (((lg + lr) & 3) << 3);
  // loop-invariant load bases
  const unsigned short* kb0 = kp + (size_t)lr * 64 + lg * 8;          // h2=0 rows
  const unsigned short* kb1 = kp + (size_t)(16 + lr) * 64 + lg * 8;   // h2=1 rows
  const unsigned short* vb0 = vp + (size_t)(lr) * 1024 + lg * 8;
  const unsigned short* vb1 = vp + (size_t)(16 + lr) * 1024 + lg * 8;
  const unsigned short* vb2 = vp + (size_t)(32 + lr) * 1024 + lg * 8;
  const unsigned short* vb3 = vp + (size_t)(48 + lr) * 1024 + lg * 8;

  short8 kc0, kc1, kc2, kc3;   // K(t)
  short8 vc0, vc1, vc2, vc3;   // V(t)
  // prologue: issue K(0)
  kc0 = *(const short8*)(kb0);
  kc1 = *(const short8*)(kb0 + 32);
  kc2 = *(const short8*)(kb1);
  kc3 = *(const short8*)(kb1 + 32);

#pragma unroll 1
  for (int kt = 0; kt < 1024; kt += 32) {
    // issue V(kt) — cover = QK + softmax
    vc0 = *(const short8*)(vb0 + kt);
    vc1 = *(const short8*)(vb1 + kt);
    vc2 = *(const short8*)(vb2 + kt);
    vc3 = *(const short8*)(vb3 + kt);
    asm volatile("s_waitcnt vmcnt(4)" ::: "memory");   // K(kt) landed (oldest 4)
    f32x4 s[2][2];
    s[0][0] = zf; s[0][1] = zf; s[1][0] = zf; s[1][1] = zf;
    __builtin_amdgcn_s_setprio(1);
    s[0][0] = MFMA16(qf[0][0], kc0, s[0][0]);
    s[0][0] = MFMA16(qf[0][1], kc1, s[0][0]);
    s[1][0] = MFMA16(qf[1][0], kc0, s[1][0]);
    s[1][0] = MFMA16(qf[1][1], kc1, s[1][0]);
    s[0][1] = MFMA16(qf[0][0], kc2, s[0][1]);
    s[0][1] = MFMA16(qf[0][1], kc3, s[0][1]);
    s[1][1] = MFMA16(qf[1][0], kc2, s[1][1]);
    s[1][1] = MFMA16(qf[1][1], kc3, s[1][1]);
    __builtin_amdgcn_s_setprio(0);
    // issue K(kt+32) — cover = softmax + P-trip + PV (~full tile)
    {
      const size_t ktn = (kt + 32 < 1024) ? (size_t)(kt + 32) : (size_t)kt;
      kc0 = *(const short8*)(kb0 + ktn * 64);
      kc1 = *(const short8*)(kb0 + ktn * 64 + 32);
      kc2 = *(const short8*)(kb1 + ktn * 64);
      kc3 = *(const short8*)(kb1 + ktn * 64 + 32);
    }
    // local maxima for both rb blocks, single fused gate
    float lmax[2][4];
    bool loc = false;
#pragma unroll
    for (int rb = 0; rb < 2; rb++)
#pragma unroll
      for (int r = 0; r < 4; r++) {
        lmax[rb][r] = fmaxf(s[rb][0][r], s[rb][1][r]);
        loc |= (lmax[rb][r] > m[rb][r] + 11.5416f);   // 8*log2e (P bound e^8)
      }
    if (__ballot(loc) != 0ull) {
#pragma unroll
      for (int rb = 0; rb < 2; rb++) {
        float mx[4];
#pragma unroll
        for (int r = 0; r < 4; r++) mx[r] = lmax[rb][r];
#pragma unroll
        for (int ofs = 1; ofs < 16; ofs <<= 1)
#pragma unroll
          for (int r = 0; r < 4; r++) mx[r] = fmaxf(mx[r], __shfl_xor(mx[r], ofs));
#pragma unroll
        for (int r = 0; r < 4; r++) {
          float mn = fmaxf(m[rb][r], mx[r]);
          float al = exp2f(m[rb][r] - mn);       // lane-uniform within row-group
          m[rb][r] = mn;
          l[rb][r] *= al;
#pragma unroll
          for (int nb = 0; nb < 4; nb++) o[rb][nb][r] *= al;
        }
      }
    }
#pragma unroll
    for (int rb = 0; rb < 2; rb++)
#pragma unroll
      for (int r = 0; r < 4; r++) {
        float p0 = exp2f(s[rb][0][r] - m[rb][r]);
        float p1 = exp2f(s[rb][1][r] - m[rb][r]);
        int q_ = lg * 4 + r;
        pw[rb * 512 + q_ * 32 + ((((lr >> 3) + q_) & 3) << 3) + (lr & 7)] = f2bf_t(p0);
        pw[rb * 512 + q_ * 32 + (((2 + (lr >> 3) + q_) & 3) << 3) + (lr & 7)] = f2bf_t(p1);
        l[rb][r] += p0 + p1;                     // per-lane partial; reduce at end
      }
    asm volatile("s_waitcnt lgkmcnt(0)" ::: "memory");   // own P writes complete
    short8 pf0 = *(const short8*)(pw + prd);
    short8 pf1 = *(const short8*)(pw + 512 + prd);
    asm volatile("s_waitcnt vmcnt(4)" ::: "memory");   // V(kt) landed; K(kt+32) in flight
    __builtin_amdgcn_s_setprio(1);
    o[0][0] = MFMA16(pf0, vc0, o[0][0]);
    o[1][0] = MFMA16(pf1, vc0, o[1][0]);
    o[0][1] = MFMA16(pf0, vc1, o[0][1]);
    o[1][1] = MFMA16(pf1, vc1, o[1][1]);
    o[0][2] = MFMA16(pf0, vc2, o[0][2]);
    o[1][2] = MFMA16(pf1, vc2, o[1][2]);
    o[0][3] = MFMA16(pf0, vc3, o[0][3]);
    o[1][3] = MFMA16(pf1, vc3, o[1][3]);
    __builtin_amdgcn_s_setprio(0);
  }
  // one-time l reduction across the 16-lane row-group (was per-tile)
#pragma unroll
  for (int ofs = 1; ofs < 16; ofs <<= 1)
#pragma unroll
    for (int rb = 0; rb < 2; rb++)
#pragma unroll
      for (int r = 0; r < 4; r++) l[rb][r] += __shfl_xor(l[rb][r], ofs);
  int b = bh >> 4, h = bh & 15;
#pragma unroll
  for (int rb = 0; rb < 2; rb++)
#pragma unroll
    for (int r = 0; r < 4; r++) {
      int n = q0 + rb * 16 + lg * 4 + r;
      size_t t = (size_t)b * 1024 + n;       // ORIGINAL token row
      float inv = 1.f / l[rb][r];
#pragma unroll
      for (int nb = 0; nb < 4; nb++)
        concat[t * CD_ + 4096 + h * 64 + nb * 16 + lr] = f2bf(o[rb][nb][r] * inv);
    }
}

// -------- final epilogue: split-K reduce + cbias + mask + residual + combine ----
// loads skipped for masked columns (dout is 4-aligned per thread quad)
__global__ __launch_bounds__(256) void final_epi(const unsigned short* __restrict__ p0,
    const unsigned short* __restrict__ p1, const float* __restrict__ cbias,
    const float* __restrict__ x, const float* __restrict__ probs,
    const int* __restrict__ emask, const int* __restrict__ pos,
    float* __restrict__ out) {
  int t = blockIdx.x;
  int c = threadIdx.x * 4;
  int dout = 2048 >> (3 - emask[t]);
  float p = probs[t];
  size_t row = (size_t)pos[t] * OD_;
  ushort4_t zz = { 0, 0, 0, 0 };
  ushort4_t m0v = zz, m1v = zz, a0v = zz, a1v = zz;
  if (c < dout) {
    m0v = *(const ushort4_t*)(p0 + row + c);
    m1v = *(const ushort4_t*)(p1 + row + c);
  }
  if (1024 + c < dout) {
    a0v = *(const ushort4_t*)(p0 + row + 1024 + c);
    a1v = *(const ushort4_t*)(p1 + row + 1024 + c);
  }
  float4 xv = *(const float4*)(x + (size_t)t * 1024 + c);
  float xa[4] = { xv.x, xv.y, xv.z, xv.w };
  float4 o;
  float oa[4];
#pragma unroll
  for (int j = 0; j < 4; j++) {
    float mlp = ((c + j) < dout ? bf2f(m0v[j]) + bf2f(m1v[j]) + cbias[c + j] : 0.f) + xa[j];
    float att = ((1024 + c + j) < dout ?
                 bf2f(a0v[j]) + bf2f(a1v[j]) + cbias[1024 + c + j] : 0.f) + xa[j];
    oa[j] = att + p * mlp;
  }
  o.x = oa[0]; o.y = oa[1]; o.z = oa[2]; o.w = oa[3];
  *(float4*)(out + (size_t)t * 1024 + c) = o;
}

extern "C" void kernel_launch(void* const* d_in, const int* in_sizes, int n_in,
                              void* d_out, int out_size, void* d_ws, size_t ws_size,
                              hipStream_t stream) {
  const float* x        = (const float*)d_in[0];
  const float* probs    = (const float*)d_in[1];
  const float* we       = (const float*)d_in[2];
  const float* mlp_bias = (const float*)d_in[3];
  const float* wc       = (const float*)d_in[4];
  const float* cbias    = (const float*)d_in[5];
  const float* n1w      = (const float*)d_in[6];
  const float* n1b      = (const float*)d_in[7];
  const float* n2w      = (const float*)d_in[8];
  const float* n2b      = (const float*)d_in[9];
  const int*   emask    = (const int*)d_in[10];
  float* out = (float*)d_out;

  char* ws = (char*)d_ws;
  size_t off = 0;
  auto alloc = [&](size_t bytes) {
    char* p = ws + off;
    off += (bytes + 255) & ~(size_t)255;
    return p;
  };
  unsigned short* we_bf = (unsigned short*)alloc((size_t)EXP_ * DIM_ * 2);
  unsigned short* wc_bf = (unsigned short*)alloc((size_t)OD_ * CD_ * 2);
  unsigned short* xn    = (unsigned short*)alloc((size_t)MPAD * DIM_ * 2); // sorted; reused as vrm
  unsigned short* qb    = (unsigned short*)alloc((size_t)NT * DIM_ * 2);
  unsigned short* kv    = (unsigned short*)alloc((size_t)NT * OD_ * 2);    // orig order
  unsigned short* kb    = (unsigned short*)alloc((size_t)NT * DIM_ * 2);
  unsigned short* vt    = (unsigned short*)alloc((size_t)NT * DIM_ * 2);
  unsigned short* cc    = (unsigned short*)alloc((size_t)NT * CD_ * 2);    // ORIGINAL order
  int* blockCnt         = (int*)alloc(32 * 4 * 4);
  int* desc             = (int*)alloc(256 * 4);
  int* perm             = (int*)alloc(MPAD * 4);
  int* pos              = (int*)alloc(NT * 4);
  unsigned short* vrm = xn;
  // split-K partials overlay xn..kb region (all dead after attn):
  // need 2 x MPAD*OD_*2 = 71.3 MB of the ~85 MB span. cc untouched.
  unsigned short* pk0 = xn;
  unsigned short* pk1 = xn + (size_t)MPAD * OD_;
  if (off > ws_size) return;  // insufficient workspace -> visible failure, no OOB

  // allow 128 KiB dynamic LDS for the 8-phase GEMM2 (host-side, not captured)
  hipFuncSetAttribute((const void*)gemm2_8p,
                      hipFuncAttributeMaxDynamicSharedMemorySize, 131072);

  count_experts<<<32, 256, 0, stream>>>(emask, blockCnt);
  scan_make<<<1, 64, 0, stream>>>(blockCnt, desc);
  fill_perm<<<34, 256, 0, stream>>>(perm);
  scatter_perm<<<32, 256, 0, stream>>>(emask, desc, perm, pos);

  cvt_bf16<<<7168, 256, 0, stream>>>(we, we_bf, EXP_ * DIM_);
  cvt_bf16<<<10240, 256, 0, stream>>>(wc, wc_bf, OD_ * CD_);
  ln1_kernel<<<2048, 256, 0, stream>>>(x, n1w, n1b, emask, pos, xn);
  gemm_grp1<<<dim3(56, NRT), 256, 0, stream>>>(xn, we_bf, mlp_bias, desc,
                                               perm, qb, kv, cc);
  ln2_kernel<<<2048, 256, 0, stream>>>(kv, n2w, n2b, kb, vrm);
  transpose_v<<<2048, 256, 0, stream>>>(vrm, vt);
  attn_kernel<<<1024, 256, 0, stream>>>(qb, kb, vt, cc);
  gemm2_8p<<<dim3(8, 34, 2), 512, 131072, stream>>>(cc, wc_bf, desc, perm, pk0, pk1);
  final_epi<<<8192, 256, 0, stream>>>(pk0, pk1, cbias, x, probs, emask, pos, out);
}

// Round 24
// 430.593 us; speedup vs baseline: 1.0794x; 1.0705x over previous
//
#include <hip/hip_runtime.h>
#include <cmath>

#define NT    8192      // B*N tokens
#define DIM_  1024
#define EXP_  7168
#define CD_   5120      // concat dim (4096 mlp + 1024 attn)
#define OD_   2048
#define MPAD  8704      // 68 row-tiles of 128 (8192 + worst-case group padding)
#define NRT   68        // row tiles (128) in sorted/padded space

typedef __attribute__((ext_vector_type(8))) short short8;
typedef __attribute__((ext_vector_type(4))) float f32x4;
typedef __attribute__((ext_vector_type(4))) unsigned short ushort4_t;

__device__ __forceinline__ unsigned short f2bf(float f) {
  union { float f; unsigned u; } v; v.f = f;
  return (unsigned short)((v.u + 0x7FFFu + ((v.u >> 16) & 1u)) >> 16);
}
// truncating bf16 (1 op); used only for P in attn (bounded, relative error <=0.4%)
__device__ __forceinline__ unsigned short f2bf_t(float f) {
  union { float f; unsigned u; } v; v.f = f;
  return (unsigned short)(v.u >> 16);
}
__device__ __forceinline__ float bf2f(unsigned short u) {
  union { unsigned u; float f; } v; v.u = ((unsigned)u) << 16;
  return v.f;
}
// tanh-form GELU (|err| vs exact erf-GELU < 1e-3); exp + hw rcp, ~9 VALU ops
__device__ __forceinline__ float fast_gelu(float x) {
  float y = 1.5957691216f * (x + 0.044715f * x * x * x);   // 2 * 0.79788456 * (...)
  float e = __expf(y);
  float t = 1.f - 2.f * __builtin_amdgcn_rcpf(1.f + e);    // tanh(y/2)
  return 0.5f * x * (1.f + t);
}

#define MFMA16(a, b, c) __builtin_amdgcn_mfma_f32_16x16x32_bf16(a, b, c, 0, 0, 0)

// ======== expert sort (128-granular): count -> scan -> fill -> scatter ========
__global__ __launch_bounds__(256) void count_experts(const int* __restrict__ em,
                                                     int* __restrict__ blockCnt) {
  __shared__ int h[4];
  int tid = threadIdx.x;
  if (tid < 4) h[tid] = 0;
  __syncthreads();
  atomicAdd(&h[em[blockIdx.x * 256 + tid]], 1);
  __syncthreads();
  if (tid < 4) blockCnt[blockIdx.x * 4 + tid] = h[tid];
}

__global__ void scan_make(const int* __restrict__ blockCnt, int* __restrict__ desc) {
  if (threadIdx.x != 0) return;
  int cnt[4] = {0, 0, 0, 0};
  for (int b = 0; b < 32; b++)
    for (int e = 0; e < 4; e++) cnt[e] += blockCnt[b * 4 + e];
  int base[4]; int acc = 0;
  for (int e = 0; e < 4; e++) { base[e] = acc; acc += ((cnt[e] + 127) >> 7) << 7; }
  for (int e = 0; e < 4; e++) { desc[e] = base[e]; desc[4 + e] = cnt[e]; }
  for (int r = 0; r < NRT; r++) {
    int te = -1;
    for (int e = 0; e < 4; e++) {
      int lo = base[e] >> 7;
      int hi = (base[e] + (((cnt[e] + 127) >> 7) << 7)) >> 7;
      if (r >= lo && r < hi) te = e;
    }
    desc[8 + r] = te;
  }
  int run[4];
  for (int e = 0; e < 4; e++) run[e] = base[e];
  for (int b = 0; b < 32; b++)
    for (int e = 0; e < 4; e++) { desc[76 + b * 4 + e] = run[e]; run[e] += blockCnt[b * 4 + e]; }
}

__global__ __launch_bounds__(256) void fill_perm(int* __restrict__ perm) {
  int i = blockIdx.x * 256 + threadIdx.x;
  if (i < MPAD) perm[i] = -1;
}

__global__ __launch_bounds__(256) void scatter_perm(const int* __restrict__ em,
    const int* __restrict__ desc, int* __restrict__ perm, int* __restrict__ pos) {
  __shared__ int wsum[4][4];
  int tid = threadIdx.x;
  int wv = tid >> 6, ln = tid & 63;
  int t = blockIdx.x * 256 + tid;
  int e = em[t];
  int wrank = 0;
#pragma unroll
  for (int k = 0; k < 4; k++) {
    unsigned long long m = __ballot(e == k);
    if (ln == 0) wsum[wv][k] = __popcll(m);
    if (e == k) wrank = __popcll(m & ((1ull << ln) - 1ull));
  }
  __syncthreads();
  int off = desc[76 + blockIdx.x * 4 + e];
  for (int w = 0; w < wv; w++) off += wsum[w][e];
  int p = off + wrank;
  perm[p] = t;
  pos[t] = p;
}

// ---------------- fp32 -> bf16 convert (both weight tensors, one launch) --------
__global__ __launch_bounds__(256) void cvt_bf16_2(const float* __restrict__ in1,
    unsigned short* __restrict__ out1, int n1, const float* __restrict__ in2,
    unsigned short* __restrict__ out2, int n2) {
  int i = (blockIdx.x * 256 + threadIdx.x) * 4;
  const float* in; unsigned short* out;
  if (i < n1) { in = in1; out = out1; }
  else { i -= n1; if (i >= n2) return; in = in2; out = out2; }
  float4 v = *(const float4*)(in + i);
  ushort4_t o;
  o[0] = f2bf(v.x); o[1] = f2bf(v.y); o[2] = f2bf(v.z); o[3] = f2bf(v.w);
  *(ushort4_t*)(out + i) = o;
}

// ---------------- LN1 + expert input mask -> xn bf16 (SORTED rows) ---------------
__global__ __launch_bounds__(256) void ln1_kernel(const float* __restrict__ x,
    const float* __restrict__ w, const float* __restrict__ b,
    const int* __restrict__ emask, const int* __restrict__ pos,
    unsigned short* __restrict__ xn) {
  int wave = threadIdx.x >> 6, lane = threadIdx.x & 63;
  int t = blockIdx.x * 4 + wave;
  const float* xt = x + (size_t)t * DIM_;
  float4 v[4];
  float s = 0.f, s2 = 0.f;
#pragma unroll
  for (int i = 0; i < 4; i++) {
    v[i] = *(const float4*)(xt + i * 256 + lane * 4);
    s  += v[i].x + v[i].y + v[i].z + v[i].w;
    s2 += v[i].x * v[i].x + v[i].y * v[i].y + v[i].z * v[i].z + v[i].w * v[i].w;
  }
#pragma unroll
  for (int o = 1; o < 64; o <<= 1) { s += __shfl_xor(s, o); s2 += __shfl_xor(s2, o); }
  float mu = s * (1.f / 1024.f);
  float rs = rsqrtf(s2 * (1.f / 1024.f) - mu * mu + 1e-5f);
  int din = 1024 >> (3 - emask[t]);
  unsigned short* ot = xn + (size_t)pos[t] * DIM_;
#pragma unroll
  for (int i = 0; i < 4; i++) {
    int c0 = i * 256 + lane * 4;
    float fv[4] = { v[i].x, v[i].y, v[i].z, v[i].w };
    ushort4_t o;
#pragma unroll
    for (int j = 0; j < 4; j++) {
      int c = c0 + j;
      float val = (c < din) ? (fv[j] - mu) * rs * w[c] + b[c] : 0.f;
      o[j] = f2bf(val);
    }
    *(ushort4_t*)(ot + c0) = o;
  }
}

// ---- GEMM1: grouped 128x128 bf16, 2-slot double buffer, 3 blocks/CU (R7) -------
// K = 128<<e per row-tile; epilogue scatters q/kv/cc to ORIGINAL token rows.
// q is pre-scaled by 0.125*log2(e) so attention softmax runs in exp2 domain.
// Epilogue: perm/bias hoisted into statically-indexed locals (one load each).
__global__ __launch_bounds__(256, 3) void gemm_grp1(
    const unsigned short* __restrict__ A, const unsigned short* __restrict__ W,
    const float* __restrict__ bias, const int* __restrict__ tdesc,
    const int* __restrict__ perm, unsigned short* __restrict__ out0,
    unsigned short* __restrict__ out1, unsigned short* __restrict__ out2) {
  __shared__ unsigned short lds[16384];          // 32 KiB: As[2][4096] | Bs[2][4096]
  unsigned short* As = lds;
  unsigned short* Bs = lds + 8192;
  const int r = blockIdx.y;
  const int e = tdesc[8 + r];
  if (e < 0) return;                             // pad tile (uniform exit)
  const int ntiles = 4 << e;                     // K = 128<<e, BK=32
  constexpr int KK = 1024;

  const int tid = threadIdx.x;
  const int lane = tid & 63;
  const int wave = tid >> 6;       // 0..3
  const int wm = wave >> 1, wn = wave & 1;
  const int lg = lane >> 4, lr = lane & 15;

  // XCD swizzle on col dim (56 % 8 == 0)
  constexpr int CPX = 56 >> 3;
  const int bx = (int)blockIdx.x;
  const int bn = (bx & 7) * CPX + (bx >> 3);
  const int n0 = bn * 128;
  const int m0 = r * 128;

  // staging source map (inverse of superrow XOR swizzle)
  const int s0g = tid >> 3,        s1g = (256 + tid) >> 3;
  const int lc0 = (tid & 7) ^ (s0g & 7), lc1 = (tid & 7) ^ (s1g & 7);
  const int row0 = 2 * s0g + (lc0 >> 2), kc0 = lc0 & 3;
  const int row1 = 2 * s1g + (lc1 >> 2), kc1 = lc1 & 3;
  const unsigned short* aS0 = A + (size_t)(m0 + row0) * KK + kc0 * 8;
  const unsigned short* aS1 = A + (size_t)(m0 + row1) * KK + kc1 * 8;
  const unsigned short* bS0 = W + (size_t)(n0 + row0) * KK + kc0 * 8;
  const unsigned short* bS1 = W + (size_t)(n0 + row1) * KK + kc1 * 8;

#define GLD(SRC, DST)                                                                \
  __builtin_amdgcn_global_load_lds(                                                  \
      (const __attribute__((address_space(1))) void*)(SRC),                          \
      (__attribute__((address_space(3))) void*)(DST), 16, 0, 0)
#define STAGE(T, SLOT) {                                                             \
    GLD(aS0 + (size_t)(T) * 32, As + (SLOT) * 4096 + tid * 8);                       \
    GLD(aS1 + (size_t)(T) * 32, As + (SLOT) * 4096 + 2048 + tid * 8);                \
    GLD(bS0 + (size_t)(T) * 32, Bs + (SLOT) * 4096 + tid * 8);                       \
    GLD(bS1 + (size_t)(T) * 32, Bs + (SLOT) * 4096 + 2048 + tid * 8);                \
  }

  const int fb = (lr >> 1) * 128 + ((((lr & 1) << 2) + lg) ^ ((lr >> 1) & 7)) * 16;
  const char* apb = (const char*)As + wm * 4096 + fb;
  const char* bpb = (const char*)Bs + wn * 4096 + fb;

  short8 afr[4], bfr[4];
#define LDFRAG(C)                                                                    \
  _Pragma("unroll") for (int mi = 0; mi < 4; mi++)                                   \
    afr[mi] = *(const short8*)(apb + (C) * 8192 + mi * 1024);                        \
  _Pragma("unroll") for (int ni = 0; ni < 4; ni++)                                   \
    bfr[ni] = *(const short8*)(bpb + (C) * 8192 + ni * 1024);

  f32x4 acc[4][4];
  f32x4 zf = { 0.f, 0.f, 0.f, 0.f };
#pragma unroll
  for (int i = 0; i < 4; i++)
#pragma unroll
    for (int j = 0; j < 4; j++) acc[i][j] = zf;

  STAGE(0, 0)
  STAGE(1, 1)
  asm volatile("s_waitcnt vmcnt(4)" ::: "memory");
  __builtin_amdgcn_s_barrier();

#pragma unroll 1
  for (int t = 0; t < ntiles; ++t) {
    const int c = t & 1;
    LDFRAG(c)
    asm volatile("s_waitcnt lgkmcnt(0)" ::: "memory");
    __builtin_amdgcn_sched_barrier(0);
    __builtin_amdgcn_s_barrier();
    const int t2 = (t + 2 < ntiles) ? t + 2 : t;
    STAGE(t2, c)
    __builtin_amdgcn_s_setprio(1);
#pragma unroll
    for (int mi = 0; mi < 4; mi++)
#pragma unroll
      for (int ni = 0; ni < 4; ni++)
        acc[mi][ni] = MFMA16(afr[mi], bfr[ni], acc[mi][ni]);
    __builtin_amdgcn_s_setprio(0);
    asm volatile("s_waitcnt vmcnt(4)" ::: "memory");
    __builtin_amdgcn_s_barrier();
  }
  asm volatile("s_waitcnt vmcnt(0)" ::: "memory");

  // epilogue: grow (sorted) = m0+wm*64+mi*16+lg*4+rr ; gcol = n0w+ni*16+lr
  // region uniform per wave; perm/bias hoisted (16 + 4 loads per thread total)
  const int n0w = n0 + wn * 64;
  int tk16[16];
  float bv4[4];
#pragma unroll
  for (int mi = 0; mi < 4; mi++)
#pragma unroll
    for (int rr = 0; rr < 4; rr++)
      tk16[mi * 4 + rr] = perm[m0 + wm * 64 + mi * 16 + lg * 4 + rr];
#pragma unroll
  for (int ni = 0; ni < 4; ni++) bv4[ni] = bias[(n0w + ni * 16 + lr) & 4095];

  if (n0w < 1024) {                    // q: scaled (0.125*log2e), head-major
#pragma unroll
    for (int mi = 0; mi < 4; mi++)
#pragma unroll
      for (int ni = 0; ni < 4; ni++)
#pragma unroll
        for (int rr = 0; rr < 4; rr++) {
          int tk = tk16[mi * 4 + rr];
          if (tk >= 0) {
            int gcol = n0w + ni * 16 + lr;
            float vv = (acc[mi][ni][rr] + bv4[ni]) * 0.18033688f;  // 0.125*log2e
            int bb = tk >> 10;
            int n = tk & 1023;
            int h = gcol >> 6;
            int d = gcol & 63;
            out0[(((size_t)(bb * 16 + h) * 1024 + n) << 6) + d] = f2bf(vv);
          }
        }
  } else if (n0w < 3072) {             // kv (pre-LN2)
#pragma unroll
    for (int mi = 0; mi < 4; mi++)
#pragma unroll
      for (int ni = 0; ni < 4; ni++)
#pragma unroll
        for (int rr = 0; rr < 4; rr++) {
          int tk = tk16[mi * 4 + rr];
          if (tk >= 0) {
            int gcol = n0w + ni * 16 + lr;
            out1[(size_t)tk * OD_ + (gcol - 1024)] = f2bf(acc[mi][ni][rr] + bv4[ni]);
          }
        }
  } else {                             // mlp hidden -> fast gelu -> cc
    const bool hasb = (n0w < 4096);    // bias covers cols [0,4096) only
#pragma unroll
    for (int mi = 0; mi < 4; mi++)
#pragma unroll
      for (int ni = 0; ni < 4; ni++)
#pragma unroll
        for (int rr = 0; rr < 4; rr++) {
          int tk = tk16[mi * 4 + rr];
          if (tk >= 0) {
            int gcol = n0w + ni * 16 + lr;
            float vb = acc[mi][ni][rr] + (hasb ? bv4[ni] : 0.f);
            out2[(size_t)tk * CD_ + (gcol - 3072)] = f2bf(fast_gelu(vb));
          }
        }
  }
#undef GLD
#undef STAGE
#undef LDFRAG
}

// ---- GEMM2: expert-sparse split-K 256x256 8-phase over SORTED rows -------------
// Row tile r = sorted rows [256r,256r+256); A-rows gathered via perm.
// Col-tiles bn >= 2^emax exit; bn rotated by r for XCD balance; split-K=2.
__global__ __launch_bounds__(512, 2) void gemm2_8p(
    const unsigned short* __restrict__ A, const unsigned short* __restrict__ W,
    const int* __restrict__ tdesc, const int* __restrict__ perm,
    unsigned short* __restrict__ pk0, unsigned short* __restrict__ pk1) {
  extern __shared__ unsigned short lds[];
  unsigned short* As = lds;            // [2 slots][16384] elems
  unsigned short* Bs = lds + 32768;
  constexpr int KK = 5120;
  constexpr int NTILES = 40;           // K half = 2560, BK=64
  const int r = blockIdx.y;            // 256-row sorted tile (34 total)
  const int ea = tdesc[8 + 2 * r];
  const int eb = tdesc[8 + 2 * r + 1];
  const int emax = (ea > eb) ? ea : eb;
  if (emax < 0) return;                // both halves pad (uniform exit)
  const int bn = ((int)blockIdx.x + r) & 7;     // rotated col-tile for XCD spread
  if (bn >= (1 << emax)) return;                // masked-out output cols
  const int k0 = (int)blockIdx.z * 2560;

  const int tid = threadIdx.x;
  const int lane = tid & 63;
  const int wave = tid >> 6;   // 0..7
  const int wm = wave >> 2;    // 0..1
  const int wn = wave & 3;     // 0..3
  const int lg = lane >> 4, lr = lane & 15;
  const int m0 = r * 256, n0 = bn * 256;

  const int srow = tid >> 3;
  const int schunk = (tid & 7) ^ (srow & 7);
  // A-row gather via perm (pad rows clamp to row 0; their outputs never gathered)
  const unsigned short* aSrcS[4];
#pragma unroll
  for (int s4 = 0; s4 < 4; s4++) {
    int tk = perm[m0 + s4 * 64 + srow];
    if (tk < 0) tk = 0;
    aSrcS[s4] = A + (size_t)tk * KK + k0 + schunk * 8;
  }
  const unsigned short* bSrc = W + (size_t)(n0 + srow) * KK + k0 + schunk * 8;

  const int xor0 = (lg ^ (lr & 7)) * 8;
  const int xor1 = ((4 + lg) ^ (lr & 7)) * 8;
  const unsigned short* ap0 = As + (wm * 64 + lr) * 64 + xor0;
  const unsigned short* ap1 = As + (wm * 64 + lr) * 64 + xor1;
  const unsigned short* bp0 = Bs + (wn * 32 + lr) * 64 + xor0;
  const unsigned short* bp1 = Bs + (wn * 32 + lr) * 64 + xor1;

#define STAGE_A(TT, SLOT, SEG)                                                       \
  __builtin_amdgcn_global_load_lds(                                                  \
    (const __attribute__((address_space(1))) void*)(aSrcS[SEG] +                     \
      (size_t)(TT) * 64),                                                            \
    (__attribute__((address_space(3))) void*)(As + (SLOT) * 16384 +                  \
      (SEG) * 4096 + tid * 8), 16, 0, 0)
#define STAGE_B(TT, SLOT, SEG)                                                       \
  __builtin_amdgcn_global_load_lds(                                                  \
    (const __attribute__((address_space(1))) void*)(bSrc +                           \
      (size_t)(SEG) * 64 * KK + (size_t)(TT) * 64),                                  \
    (__attribute__((address_space(3))) void*)(Bs + (SLOT) * 16384 +                  \
      (SEG) * 4096 + tid * 8), 16, 0, 0)

  short8 afr[4][2], bfr[2][2][2];
#define LDFRAG_A(C, QM)                                                              \
  _Pragma("unroll") for (int mi = 0; mi < 4; mi++) {                                 \
    afr[mi][0] = *(const short8*)(ap0 + (C) * 16384 + (QM) * 8192 + mi * 1024);      \
    afr[mi][1] = *(const short8*)(ap1 + (C) * 16384 + (QM) * 8192 + mi * 1024);      \
  }
#define LDFRAG_B(C, QN)                                                              \
  _Pragma("unroll") for (int ni = 0; ni < 2; ni++) {                                 \
    bfr[QN][ni][0] = *(const short8*)(bp0 + (C) * 16384 + (QN) * 8192 + ni * 1024);  \
    bfr[QN][ni][1] = *(const short8*)(bp1 + (C) * 16384 + (QN) * 8192 + ni * 1024);  \
  }
#define DOMFMA(QM, QN)                                                               \
  __builtin_amdgcn_s_setprio(1);                                                     \
  _Pragma("unroll") for (int mi = 0; mi < 4; mi++)                                   \
  _Pragma("unroll") for (int ni = 0; ni < 2; ni++) {                                 \
    acc[(QM) * 4 + mi][(QN) * 2 + ni] =                                              \
        MFMA16(afr[mi][0], bfr[QN][ni][0], acc[(QM) * 4 + mi][(QN) * 2 + ni]);       \
    acc[(QM) * 4 + mi][(QN) * 2 + ni] =                                              \
        MFMA16(afr[mi][1], bfr[QN][ni][1], acc[(QM) * 4 + mi][(QN) * 2 + ni]);       \
  }                                                                                  \
  __builtin_amdgcn_s_setprio(0);

#define SCHED0 __builtin_amdgcn_sched_barrier(0)

#define TILE_BODY(T, C) {                                                            \
    const int tn1 = ((T) + 1 < NTILES) ? (T) + 1 : NTILES - 1;                       \
    const int tn2 = ((T) + 2 < NTILES) ? (T) + 2 : NTILES - 1;                       \
    LDFRAG_A(C, 0); LDFRAG_B(C, 0);                                                  \
    STAGE_B(tn1, (C) ^ 1, 2); STAGE_B(tn1, (C) ^ 1, 3);                              \
    SCHED0;                                                                          \
    __builtin_amdgcn_s_barrier();                                                    \
    asm volatile("s_waitcnt lgkmcnt(0)");                                            \
    SCHED0;                                                                          \
    DOMFMA(0, 0);                                                                    \
    asm volatile("s_waitcnt vmcnt(6)" ::: "memory");                                 \
    __builtin_amdgcn_s_barrier();                                                    \
    LDFRAG_B(C, 1);                                                                  \
    STAGE_A(tn1, (C) ^ 1, 2); STAGE_A(tn1, (C) ^ 1, 3);                              \
    SCHED0;                                                                          \
    __builtin_amdgcn_s_barrier();                                                    \
    asm volatile("s_waitcnt lgkmcnt(0)");                                            \
    SCHED0;                                                                          \
    DOMFMA(0, 1);                                                                    \
    __builtin_amdgcn_s_barrier();                                                    \
    LDFRAG_A(C, 1);                                                                  \
    STAGE_A(tn2, (C), 0); STAGE_A(tn2, (C), 1);                                      \
    SCHED0;                                                                          \
    __builtin_amdgcn_s_barrier();                                                    \
    asm volatile("s_waitcnt lgkmcnt(0)");                                            \
    SCHED0;                                                                          \
    DOMFMA(1, 0);                                                                    \
    __builtin_amdgcn_s_barrier();                                                    \
    STAGE_B(tn2, (C), 0); STAGE_B(tn2, (C), 1);                                      \
    SCHED0;                                                                          \
    __builtin_amdgcn_s_barrier();                                                    \
    DOMFMA(1, 1);                                                                    \
    asm volatile("s_waitcnt vmcnt(8)" ::: "memory");                                 \
    __builtin_amdgcn_s_barrier();                                                    \
  }

  f32x4 acc[8][4];
  f32x4 zf = { 0.f, 0.f, 0.f, 0.f };
#pragma unroll
  for (int i = 0; i < 8; i++)
#pragma unroll
    for (int j = 0; j < 4; j++) acc[i][j] = zf;

  STAGE_A(0, 0, 0); STAGE_A(0, 0, 1); STAGE_A(0, 0, 2); STAGE_A(0, 0, 3);
  STAGE_B(0, 0, 0); STAGE_B(0, 0, 1); STAGE_B(0, 0, 2); STAGE_B(0, 0, 3);
  STAGE_A(1, 1, 0); STAGE_A(1, 1, 1);
  STAGE_B(1, 1, 0); STAGE_B(1, 1, 1);
  asm volatile("s_waitcnt vmcnt(4)" ::: "memory");
  __builtin_amdgcn_s_barrier();

#pragma unroll 1
  for (int tp = 0; tp < NTILES / 2; ++tp) {
    TILE_BODY(2 * tp, 0)
    TILE_BODY(2 * tp + 1, 1)
  }
  asm volatile("s_waitcnt vmcnt(0)" ::: "memory");

  // epilogue: bf16 partial (no bias) at SORTED row grow
  unsigned short* dst = blockIdx.z ? pk1 : pk0;
#pragma unroll
  for (int mi8 = 0; mi8 < 8; mi8++) {
#pragma unroll
    for (int nj = 0; nj < 4; nj++) {
#pragma unroll
      for (int r2 = 0; r2 < 4; r2++) {
        int grow = m0 + wm * 64 + (mi8 >> 2) * 128 + (mi8 & 3) * 16 + lg * 4 + r2;
        int gcol = n0 + wn * 32 + (nj >> 1) * 128 + (nj & 1) * 16 + lr;
        dst[(size_t)grow * OD_ + gcol] = f2bf(acc[mi8][nj][r2]);
      }
    }
  }
#undef STAGE_A
#undef STAGE_B
#undef LDFRAG_A
#undef LDFRAG_B
#undef DOMFMA
#undef SCHED0
#undef TILE_BODY
}

// ---------------- LN2 over 2048 -> k (head-major bf16), v (row-major bf16) ------
__global__ __launch_bounds__(256) void ln2_kernel(const unsigned short* __restrict__ kv,
    const float* __restrict__ w, const float* __restrict__ b,
    unsigned short* __restrict__ kb, unsigned short* __restrict__ vrm) {
  int wave = threadIdx.x >> 6, lane = threadIdx.x & 63;
  int t = blockIdx.x * 4 + wave;
  const unsigned short* p = kv + (size_t)t * OD_;
  float vals[4][8];
  float s = 0.f, s2 = 0.f;
#pragma unroll
  for (int i = 0; i < 4; i++) {
    short8 v = *(const short8*)(p + i * 512 + lane * 8);
#pragma unroll
    for (int j = 0; j < 8; j++) {
      float f = bf2f((unsigned short)v[j]);
      vals[i][j] = f; s += f; s2 += f * f;
    }
  }
#pragma unroll
  for (int o = 1; o < 64; o <<= 1) { s += __shfl_xor(s, o); s2 += __shfl_xor(s2, o); }
  float mu = s * (1.f / 2048.f);
  float rs = rsqrtf(s2 * (1.f / 2048.f) - mu * mu + 1e-5f);
  int bidx = t >> 10, n = t & 1023;
#pragma unroll
  for (int i = 0; i < 4; i++) {
    int c0 = i * 512 + lane * 8;
    short8 o8;
#pragma unroll
    for (int j = 0; j < 8; j++) {
      int c = c0 + j;
      o8[j] = (short)f2bf((vals[i][j] - mu) * rs * w[c] + b[c]);
    }
    if (c0 < 1024) {
      int h = c0 >> 6, d = c0 & 63;
      *(short8*)(kb + (((size_t)(bidx * 16 + h) * 1024 + n) << 6) + d) = o8;
    } else {
      *(short8*)(vrm + (size_t)t * 1024 + (c0 - 1024)) = o8;
    }
  }
}

// ---------------- V transpose: [b,n,h*64+d] -> [b,h,d,n] ----------------
__global__ __launch_bounds__(256) void transpose_v(const unsigned short* __restrict__ vrm,
                                                   unsigned short* __restrict__ vt) {
  int bh = blockIdx.x >> 4;
  int nblk = (blockIdx.x & 15) * 64;
  int b = bh >> 4, h = bh & 15;
  __shared__ unsigned short tile[64][65];
  int tid = threadIdx.x;
  int i = tid >> 2;
  int d0 = (tid & 3) * 16;
  const unsigned short* src = vrm + ((size_t)(b * 1024 + nblk + i)) * 1024 + h * 64 + d0;
  short8 v0 = *(const short8*)(src);
  short8 v1 = *(const short8*)(src + 8);
#pragma unroll
  for (int j = 0; j < 8; j++) {
    tile[d0 + j][i] = (unsigned short)v0[j];
    tile[d0 + 8 + j][i] = (unsigned short)v1[j];
  }
  __syncthreads();
  int d = tid >> 2;
  int i0 = (tid & 3) * 16;
  unsigned short* dst = vt + ((size_t)bh * 64 + d) * 1024 + nblk + i0;
  short8 o0, o1;
#pragma unroll
  for (int j = 0; j < 8; j++) { o0[j] = (short)tile[d][i0 + j]; o1[j] = (short)tile[d][i0 + 8 + j]; }
  *(short8*)dst = o0;
  *(short8*)(dst + 8) = o1;
}

// ---- flash attention: 256 thr / 4 waves, wave-private swizzled P, defer-max
// ---- (single fused skip gate, threshold 16*log2e), register-pipelined K/V,
// ---- XCD-affine block map; exp2-domain softmax; lazy l-reduction; truncating P
__global__ __launch_bounds__(256) void attn_kernel(const unsigned short* __restrict__ q,
    const unsigned short* __restrict__ k, const unsigned short* __restrict__ vt,
    unsigned short* __restrict__ concat) {
  int bid = blockIdx.x;
  int bh = (bid & 7) + 8 * ((bid >> 3) & 15);      // bh%8 == bid%8 -> XCD affinity
  int wv = threadIdx.x >> 6;
  int q0 = ((bid >> 7) & 7) * 128 + wv * 32;
  int lane = threadIdx.x & 63;
  int lg = lane >> 4, lr = lane & 15;
  __shared__ unsigned short plds[4][2][512];
  unsigned short* pw = &plds[wv][0][0];
  const unsigned short* qp = q + (size_t)bh * (1024 * 64);
  const unsigned short* kp = k + (size_t)bh * (1024 * 64);
  const unsigned short* vp = vt + (size_t)bh * (64 * 1024);
  short8 qf[2][2];
#pragma unroll
  for (int rb = 0; rb < 2; rb++)
#pragma unroll
    for (int c = 0; c < 2; c++)
      qf[rb][c] = *(const short8*)(qp + (q0 + rb * 16 + lr) * 64 + c * 32 + lg * 8);
  f32x4 zf = { 0.f, 0.f, 0.f, 0.f };
  f32x4 o[2][4];
  float m[2][4], l[2][4];
#pragma unroll
  for (int rb = 0; rb < 2; rb++) {
#pragma unroll
    for (int r = 0; r < 4; r++) { m[rb][r] = -1e30f; l[rb][r] = 0.f; }
#pragma unroll
    for (int nb = 0; nb < 4; nb++) o[rb][nb] = zf;
  }
  const int prd = lr * 32 + (((lg + lr) & 3) << 3);
  // loop-invariant load bases
  const unsigned short* kb0 = kp + (size_t)lr * 64 + lg * 8;          // h2=0 rows
  const unsigned short* kb1 = kp + (size_t)(16 + lr) * 64 + lg * 8;   // h2=1 rows
  const unsigned short* vb0 = vp + (size_t)(lr) * 1024 + lg * 8;
  const unsigned short* vb1 = vp + (size_t)(16 + lr) * 1024 + lg * 8;
  const unsigned short* vb2 = vp + (size_t)(32 + lr) * 1024 + lg * 8;
  const unsigned short* vb3 = vp + (size_t)(48 + lr) * 1024 + lg * 8;

  short8 kc0, kc1, kc2, kc3;   // K(t)
  short8 vc0, vc1, vc2, vc3;   // V(t)
  // prologue: issue K(0)
  kc0 = *(const short8*)(kb0);
  kc1 = *(const short8*)(kb0 + 32);
  kc2 = *(const short8*)(kb1);
  kc3 = *(const short8*)(kb1 + 32);

#pragma unroll 1
  for (int kt = 0; kt < 1024; kt += 32) {
    // issue V(kt) — cover = QK + softmax
    vc0 = *(const short8*)(vb0 + kt);
    vc1 = *(const short8*)(vb1 + kt);
    vc2 = *(const short8*)(vb2 + kt);
    vc3 = *(const short8*)(vb3 + kt);
    asm volatile("s_waitcnt vmcnt(4)" ::: "memory");   // K(kt) landed (oldest 4)
    f32x4 s[2][2];
    s[0][0] = zf; s[0][1] = zf; s[1][0] = zf; s[1][1] = zf;
    __builtin_amdgcn_s_setprio(1);
    s[0][0] = MFMA16(qf[0][0], kc0, s[0][0]);
    s[0][0] = MFMA16(qf[0][1], kc1, s[0][0]);
    s[1][0] = MFMA16(qf[1][0], kc0, s[1][0]);
    s[1][0] = MFMA16(qf[1][1], kc1, s[1][0]);
    s[0][1] = MFMA16(qf[0][0], kc2, s[0][1]);
    s[0][1] = MFMA16(qf[0][1], kc3, s[0][1]);
    s[1][1] = MFMA16(qf[1][0], kc2, s[1][1]);
    s[1][1] = MFMA16(qf[1][1], kc3, s[1][1]);
    __builtin_amdgcn_s_setprio(0);
    // issue K(kt+32) — cover = softmax + P-trip + PV (~full tile)
    {
      const size_t ktn = (kt + 32 < 1024) ? (size_t)(kt + 32) : (size_t)kt;
      kc0 = *(const short8*)(kb0 + ktn * 64);
      kc1 = *(const short8*)(kb0 + ktn * 64 + 32);
      kc2 = *(const short8*)(kb1 + ktn * 64);
      kc3 = *(const short8*)(kb1 + ktn * 64 + 32);
    }
    // local maxima for both rb blocks, single fused gate
    float lmax[2][4];
    bool loc = false;
#pragma unroll
    for (int rb = 0; rb < 2; rb++)
#pragma unroll
      for (int r = 0; r < 4; r++) {
        lmax[rb][r] = fmaxf(s[rb][0][r], s[rb][1][r]);
        loc |= (lmax[rb][r] > m[rb][r] + 23.083f);   // 16*log2e (P bound e^16)
      }
    if (__ballot(loc) != 0ull) {
#pragma unroll
      for (int rb = 0; rb < 2; rb++) {
        float mx[4];
#pragma unroll
        for (int r = 0; r < 4; r++) mx[r] = lmax[rb][r];
#pragma unroll
        for (int ofs = 1; ofs < 16; ofs <<= 1)
#pragma unroll
          for (int r = 0; r < 4; r++) mx[r] = fmaxf(mx[r], __shfl_xor(mx[r], ofs));
#pragma unroll
        for (int r = 0; r < 4; r++) {
          float mn = fmaxf(m[rb][r], mx[r]);
          float al = exp2f(m[rb][r] - mn);       // lane-uniform within row-group
          m[rb][r] = mn;
          l[rb][r] *= al;
#pragma unroll
          for (int nb = 0; nb < 4; nb++) o[rb][nb][r] *= al;
        }
      }
    }
#pragma unroll
    for (int rb = 0; rb < 2; rb++)
#pragma unroll
      for (int r = 0; r < 4; r++) {
        float p0 = exp2f(s[rb][0][r] - m[rb][r]);
        float p1 = exp2f(s[rb][1][r] - m[rb][r]);
        int q_ = lg * 4 + r;
        pw[rb * 512 + q_ * 32 + ((((lr >> 3) + q_) & 3) << 3) + (lr & 7)] = f2bf_t(p0);
        pw[rb * 512 + q_ * 32 + (((2 + (lr >> 3) + q_) & 3) << 3) + (lr & 7)] = f2bf_t(p1);
        l[rb][r] += p0 + p1;                     // per-lane partial; reduce at end
      }
    asm volatile("s_waitcnt lgkmcnt(0)" ::: "memory");   // own P writes complete
    short8 pf0 = *(const short8*)(pw + prd);
    short8 pf1 = *(const short8*)(pw + 512 + prd);
    asm volatile("s_waitcnt vmcnt(4)" ::: "memory");   // V(kt) landed; K(kt+32) in flight
    __builtin_amdgcn_s_setprio(1);
    o[0][0] = MFMA16(pf0, vc0, o[0][0]);
    o[1][0] = MFMA16(pf1, vc0, o[1][0]);
    o[0][1] = MFMA16(pf0, vc1, o[0][1]);
    o[1][1] = MFMA16(pf1, vc1, o[1][1]);
    o[0][2] = MFMA16(pf0, vc2, o[0][2]);
    o[1][2] = MFMA16(pf1, vc2, o[1][2]);
    o[0][3] = MFMA16(pf0, vc3, o[0][3]);
    o[1][3] = MFMA16(pf1, vc3, o[1][3]);
    __builtin_amdgcn_s_setprio(0);
  }
  // one-time l reduction across the 16-lane row-group (was per-tile)
#pragma unroll
  for (int ofs = 1; ofs < 16; ofs <<= 1)
#pragma unroll
    for (int rb = 0; rb < 2; rb++)
#pragma unroll
      for (int r = 0; r < 4; r++) l[rb][r] += __shfl_xor(l[rb][r], ofs);
  int b = bh >> 4, h = bh & 15;
#pragma unroll
  for (int rb = 0; rb < 2; rb++)
#pragma unroll
    for (int r = 0; r < 4; r++) {
      int n = q0 + rb * 16 + lg * 4 + r;
      size_t t = (size_t)b * 1024 + n;       // ORIGINAL token row
      float inv = 1.f / l[rb][r];
#pragma unroll
      for (int nb = 0; nb < 4; nb++)
        concat[t * CD_ + 4096 + h * 64 + nb * 16 + lr] = f2bf(o[rb][nb][r] * inv);
    }
}

// -------- final epilogue: split-K reduce + cbias + mask + residual + combine ----
// loads skipped for masked columns (dout is 4-aligned per thread quad)
__global__ __launch_bounds__(256) void final_epi(const unsigned short* __restrict__ p0,
    const unsigned short* __restrict__ p1, const float* __restrict__ cbias,
    const float* __restrict__ x, const float* __restrict__ probs,
    const int* __restrict__ emask, const int* __restrict__ pos,
    float* __restrict__ out) {
  int t = blockIdx.x;
  int c = threadIdx.x * 4;
  int dout = 2048 >> (3 - emask[t]);
  float p = probs[t];
  size_t row = (size_t)pos[t] * OD_;
  ushort4_t zz = { 0, 0, 0, 0 };
  ushort4_t m0v = zz, m1v = zz, a0v = zz, a1v = zz;
  if (c < dout) {
    m0v = *(const ushort4_t*)(p0 + row + c);
    m1v = *(const ushort4_t*)(p1 + row + c);
  }
  if (1024 + c < dout) {
    a0v = *(const ushort4_t*)(p0 + row + 1024 + c);
    a1v = *(const ushort4_t*)(p1 + row + 1024 + c);
  }
  float4 xv = *(const float4*)(x + (size_t)t * 1024 + c);
  float xa[4] = { xv.x, xv.y, xv.z, xv.w };
  float4 o;
  float oa[4];
#pragma unroll
  for (int j = 0; j < 4; j++) {
    float mlp = ((c + j) < dout ? bf2f(m0v[j]) + bf2f(m1v[j]) + cbias[c + j] : 0.f) + xa[j];
    float att = ((1024 + c + j) < dout ?
                 bf2f(a0v[j]) + bf2f(a1v[j]) + cbias[1024 + c + j] : 0.f) + xa[j];
    oa[j] = att + p * mlp;
  }
  o.x = oa[0]; o.y = oa[1]; o.z = oa[2]; o.w = oa[3];
  *(float4*)(out + (size_t)t * 1024 + c) = o;
}

extern "C" void kernel_launch(void* const* d_in, const int* in_sizes, int n_in,
                              void* d_out, int out_size, void* d_ws, size_t ws_size,
                              hipStream_t stream) {
  const float* x        = (const float*)d_in[0];
  const float* probs    = (const float*)d_in[1];
  const float* we       = (const float*)d_in[2];
  const float* mlp_bias = (const float*)d_in[3];
  const float* wc       = (const float*)d_in[4];
  const float* cbias    = (const float*)d_in[5];
  const float* n1w      = (const float*)d_in[6];
  const float* n1b      = (const float*)d_in[7];
  const float* n2w      = (const float*)d_in[8];
  const float* n2b      = (const float*)d_in[9];
  const int*   emask    = (const int*)d_in[10];
  float* out = (float*)d_out;

  char* ws = (char*)d_ws;
  size_t off = 0;
  auto alloc = [&](size_t bytes) {
    char* p = ws + off;
    off += (bytes + 255) & ~(size_t)255;
    return p;
  };
  unsigned short* we_bf = (unsigned short*)alloc((size_t)EXP_ * DIM_ * 2);
  unsigned short* wc_bf = (unsigned short*)alloc((size_t)OD_ * CD_ * 2);
  unsigned short* xn    = (unsigned short*)alloc((size_t)MPAD * DIM_ * 2); // sorted; reused as vrm
  unsigned short* qb    = (unsigned short*)alloc((size_t)NT * DIM_ * 2);
  unsigned short* kv    = (unsigned short*)alloc((size_t)NT * OD_ * 2);    // orig order
  unsigned short* kb    = (unsigned short*)alloc((size_t)NT * DIM_ * 2);
  unsigned short* vt    = (unsigned short*)alloc((size_t)NT * DIM_ * 2);
  unsigned short* cc    = (unsigned short*)alloc((size_t)NT * CD_ * 2);    // ORIGINAL order
  int* blockCnt         = (int*)alloc(32 * 4 * 4);
  int* desc             = (int*)alloc(256 * 4);
  int* perm             = (int*)alloc(MPAD * 4);
  int* pos              = (int*)alloc(NT * 4);
  unsigned short* vrm = xn;
  // split-K partials overlay xn..kb region (all dead after attn):
  // need 2 x MPAD*OD_*2 = 71.3 MB of the ~85 MB span. cc untouched.
  unsigned short* pk0 = xn;
  unsigned short* pk1 = xn + (size_t)MPAD * OD_;
  if (off > ws_size) return;  // insufficient workspace -> visible failure, no OOB

  // allow 128 KiB dynamic LDS for the 8-phase GEMM2 (host-side, not captured)
  hipFuncSetAttribute((const void*)gemm2_8p,
                      hipFuncAttributeMaxDynamicSharedMemorySize, 131072);

  count_experts<<<32, 256, 0, stream>>>(emask, blockCnt);
  scan_make<<<1, 64, 0, stream>>>(blockCnt, desc);
  fill_perm<<<34, 256, 0, stream>>>(perm);
  scatter_perm<<<32, 256, 0, stream>>>(emask, desc, perm, pos);

  cvt_bf16_2<<<17408, 256, 0, stream>>>(we, we_bf, EXP_ * DIM_,
                                        wc, wc_bf, OD_ * CD_);
  ln1_kernel<<<2048, 256, 0, stream>>>(x, n1w, n1b, emask, pos, xn);
  gemm_grp1<<<dim3(56, NRT), 256, 0, stream>>>(xn, we_bf, mlp_bias, desc,
                                               perm, qb, kv, cc);
  ln2_kernel<<<2048, 256, 0, stream>>>(kv, n2w, n2b, kb, vrm);
  transpose_v<<<2048, 256, 0, stream>>>(vrm, vt);
  attn_kernel<<<1024, 256, 0, stream>>>(qb, kb, vt, cc);
  gemm2_8p<<<dim3(8, 34, 2), 512, 131072, stream>>>(cc, wc_bf, desc, perm, pk0, pk1);
  final_epi<<<8192, 256, 0, stream>>>(pk0, pk1, cbias, x, probs, emask, pos, out);
}